// Round 2
// baseline (49727.075 us; speedup 1.0000x reference)
//
#include <hip/hip_runtime.h>
#include <hip/hip_bf16.h>

#define NH 8
#define DH 16

// PyTorch-style sinusoidal PE: pe[pos, 2j] = sin(pos*div_j), pe[pos,2j+1] = cos(pos*div_j)
// div_j = exp(-2j*ln(10000)/128) = exp(-j*ln(10000)/64)
__device__ __forceinline__ float pe_val(int pos, int d) {
    int j = d >> 1;
    float div = expf((float)j * -0.14391156831212787f);
    float ang = (float)pos * div;
    return (d & 1) ? cosf(ang) : sinf(ang);
}

// s[b*64+i, d] = emb[src[b,i]][d]*sqrt(128) + pe(i, d)   (total 32*64*128 elems)
__global__ void embed_kernel(const int* __restrict__ src, const float* __restrict__ emb,
                             float* __restrict__ S) {
    int idx = blockIdx.x * 256 + threadIdx.x;
    int d = idx & 127;
    int n = idx >> 7;       // b*64 + i
    int i = n & 63;
    int tok = src[n];
    S[idx] = emb[tok * 128 + d] * 11.313708498984761f + pe_val(i, d);
}

// t[b*1024+i, d] = tgt[...] + pe(i, d)   (total 32*1024*128 elems)
__global__ void addpe_kernel(const float* __restrict__ tgt, float* __restrict__ T) {
    int idx = blockIdx.x * 256 + threadIdx.x;
    int d = idx & 127;
    int n = idx >> 7;
    int i = n & 1023;
    T[idx] = tgt[idx] + pe_val(i, d);
}

// C[m,n] = sum_k A[m,k] * W[n,k] + bias[n]   (y = x @ W.T + b), optional ReLU.
// M,N,K all multiples of 16.
__global__ void gemm_xWt(const float* __restrict__ A, const float* __restrict__ W,
                         const float* __restrict__ bias, float* __restrict__ C,
                         int M, int N, int K, int relu) {
    __shared__ float As[16][17];
    __shared__ float Ws[16][17];
    int tx = threadIdx.x, ty = threadIdx.y;
    int m = blockIdx.y * 16 + ty;
    int nBase = blockIdx.x * 16;
    int n = nBase + tx;
    float acc = 0.f;
    for (int k0 = 0; k0 < K; k0 += 16) {
        As[ty][tx] = A[(size_t)m * K + k0 + tx];
        Ws[ty][tx] = W[(size_t)(nBase + ty) * K + k0 + tx];
        __syncthreads();
#pragma unroll
        for (int k = 0; k < 16; k++) acc += As[ty][k] * Ws[tx][k];
        __syncthreads();
    }
    float v = acc + bias[n];
    if (relu) v = fmaxf(v, 0.f);
    C[(size_t)m * N + n] = v;
}

// One wave (64 lanes) per (b, h, q). Two-pass softmax, scores cached in regs.
// NK = SKV/64. Q/K/V are fp32 buffers with given row stride and column offset;
// head h uses columns [off + h*16, off + h*16 + 16).
template <int NK>
__global__ void attn_kernel(const float* __restrict__ Qb, int qstride, int qoff,
                            const float* __restrict__ Kb, int kstride, int koff,
                            const float* __restrict__ Vb, int vstride, int voff,
                            float* __restrict__ O, int SQ, int SKV) {
    int wid = blockIdx.x;
    int lane = threadIdx.x;
    int q = wid % SQ;
    int h = (wid / SQ) % NH;
    int b = wid / (SQ * NH);

    const float* qp = Qb + (size_t)(b * SQ + q) * qstride + qoff + h * DH;
    float qv[DH];
#pragma unroll
    for (int d = 0; d < DH; d++) qv[d] = qp[d];

    float sc[NK];
    float mmax = -1e30f;
#pragma unroll
    for (int jj = 0; jj < NK; jj++) {
        int j = lane + 64 * jj;
        const float* kp = Kb + (size_t)(b * SKV + j) * kstride + koff + h * DH;
        float s = 0.f;
#pragma unroll
        for (int d = 0; d < DH; d++) s += qv[d] * kp[d];
        sc[jj] = s * 0.25f;  // 1/sqrt(16)
        mmax = fmaxf(mmax, sc[jj]);
    }
    for (int off = 32; off; off >>= 1) mmax = fmaxf(mmax, __shfl_xor(mmax, off));

    float lsum = 0.f;
    float acc[DH];
#pragma unroll
    for (int d = 0; d < DH; d++) acc[d] = 0.f;
#pragma unroll
    for (int jj = 0; jj < NK; jj++) {
        int j = lane + 64 * jj;
        float p = __expf(sc[jj] - mmax);
        lsum += p;
        const float* vp = Vb + (size_t)(b * SKV + j) * vstride + voff + h * DH;
#pragma unroll
        for (int d = 0; d < DH; d++) acc[d] += p * vp[d];
    }
    for (int off = 32; off; off >>= 1) lsum += __shfl_xor(lsum, off);
#pragma unroll
    for (int d = 0; d < DH; d++)
        for (int off = 32; off; off >>= 1) acc[d] += __shfl_xor(acc[d], off);

    if (lane == 0) {
        float inv = 1.f / lsum;
        float* op = O + (size_t)(b * SQ + q) * 128 + h * DH;
#pragma unroll
        for (int d = 0; d < DH; d++) op[d] = acc[d] * inv;
    }
}

// Y[r,:] = LN(X[r,:] + R[r,:]) * g + b over 128 cols. One wave per row.
__global__ void ln_kernel(const float* __restrict__ X, const float* __restrict__ R,
                          const float* __restrict__ g, const float* __restrict__ bta,
                          float* __restrict__ Y) {
    int r = blockIdx.x;
    int lane = threadIdx.x;
    size_t base = (size_t)r * 128;
    float x0 = X[base + lane], x1 = X[base + lane + 64];
    if (R) { x0 += R[base + lane]; x1 += R[base + lane + 64]; }
    float s = x0 + x1;
    for (int off = 32; off; off >>= 1) s += __shfl_xor(s, off);
    float mean = s * (1.f / 128.f);
    float d0 = x0 - mean, d1 = x1 - mean;
    float vs = d0 * d0 + d1 * d1;
    for (int off = 32; off; off >>= 1) vs += __shfl_xor(vs, off);
    float rstd = rsqrtf(vs * (1.f / 128.f) + 1e-5f);
    Y[base + lane] = d0 * rstd * g[lane] + bta[lane];
    Y[base + lane + 64] = d1 * rstd * g[lane + 64] + bta[lane + 64];
}

// out[r] = dot(X[r,:], w) + b   (128 cols, one wave per row), fp32 out
__global__ void fc_kernel(const float* __restrict__ X, const float* __restrict__ w,
                          const float* __restrict__ b, float* __restrict__ out) {
    int r = blockIdx.x;
    int lane = threadIdx.x;
    size_t base = (size_t)r * 128;
    float s = X[base + lane] * w[lane] + X[base + lane + 64] * w[lane + 64];
    for (int off = 32; off; off >>= 1) s += __shfl_xor(s, off);
    if (lane == 0) out[r] = s + b[0];
}

static inline void gemm(const float* A, const float* W, const float* bias, float* C,
                        int M, int N, int K, int relu, hipStream_t st) {
    dim3 g(N / 16, M / 16), blk(16, 16);
    hipLaunchKernelGGL(gemm_xWt, g, blk, 0, st, A, W, bias, C, M, N, K, relu);
}

extern "C" void kernel_launch(void* const* d_in, const int* in_sizes, int n_in,
                              void* d_out, int out_size, void* d_ws, size_t ws_size,
                              hipStream_t stream) {
    const int B = 32, SSRC = 64, STGT = 1024, D = 128, DFF_ = 512, LE = 6, LD = 6;

    const int*   src = (const int*)d_in[0];
    const float* tgt = (const float*)d_in[1];
    const float* emb = (const float*)d_in[2];
    const float* enc_qkv_w = (const float*)d_in[3];
    const float* enc_qkv_b = (const float*)d_in[4];
    const float* enc_out_w = (const float*)d_in[5];
    const float* enc_out_b = (const float*)d_in[6];
    const float* enc_ln1_g = (const float*)d_in[7];
    const float* enc_ln1_b = (const float*)d_in[8];
    const float* enc_ff1_w = (const float*)d_in[9];
    const float* enc_ff1_b = (const float*)d_in[10];
    const float* enc_ff2_w = (const float*)d_in[11];
    const float* enc_ff2_b = (const float*)d_in[12];
    const float* enc_ln2_g = (const float*)d_in[13];
    const float* enc_ln2_b = (const float*)d_in[14];
    const float* enc_norm_g = (const float*)d_in[15];
    const float* enc_norm_b = (const float*)d_in[16];
    const float* dec_sa_qkv_w = (const float*)d_in[17];
    const float* dec_sa_qkv_b = (const float*)d_in[18];
    const float* dec_sa_out_w = (const float*)d_in[19];
    const float* dec_sa_out_b = (const float*)d_in[20];
    const float* dec_ln1_g = (const float*)d_in[21];
    const float* dec_ln1_b = (const float*)d_in[22];
    const float* dec_ca_qkv_w = (const float*)d_in[23];
    const float* dec_ca_qkv_b = (const float*)d_in[24];
    const float* dec_ca_out_w = (const float*)d_in[25];
    const float* dec_ca_out_b = (const float*)d_in[26];
    const float* dec_ln2_g = (const float*)d_in[27];
    const float* dec_ln2_b = (const float*)d_in[28];
    const float* dec_ff1_w = (const float*)d_in[29];
    const float* dec_ff1_b = (const float*)d_in[30];
    const float* dec_ff2_w = (const float*)d_in[31];
    const float* dec_ff2_b = (const float*)d_in[32];
    const float* dec_ln3_g = (const float*)d_in[33];
    const float* dec_ln3_b = (const float*)d_in[34];
    const float* dec_norm_g = (const float*)d_in[35];
    const float* dec_norm_b = (const float*)d_in[36];
    const float* fc_w = (const float*)d_in[37];
    const float* fc_b = (const float*)d_in[38];

    const int NT = B * STGT;   // 32768 decoder rows
    const int NS = B * SSRC;   // 2048 encoder rows

    float* ws = (float*)d_ws;
    float* t   = ws;                      // 32768*128 = 4,194,304
    float* s   = t + (size_t)NT * D;      // 2048*128  =   262,144
    float* mem = s + (size_t)NS * D;      // 2048*128  =   262,144
    float* sc1 = mem + (size_t)NS * D;    // 32768*512 = 16,777,216 (qkv / ffn-hidden)
    float* sc2 = sc1 + (size_t)NT * DFF_; // 32768*128 =  4,194,304 (attn out)
    float* sc3 = sc2 + (size_t)NT * D;    // 2048*256  =    524,288 (cross KV)

    // ---------------- Encoder ----------------
    hipLaunchKernelGGL(embed_kernel, dim3(NS * D / 256), dim3(256), 0, stream, src, emb, s);

    for (int i = 0; i < LE; i++) {
        const float* Wqkv = enc_qkv_w + (size_t)i * 3 * D * D;
        const float* bqkv = enc_qkv_b + (size_t)i * 3 * D;
        gemm(s, Wqkv, bqkv, sc1, NS, 3 * D, D, 0, stream);
        hipLaunchKernelGGL((attn_kernel<1>), dim3(B * NH * SSRC), dim3(64), 0, stream,
                           sc1, 3 * D, 0, sc1, 3 * D, D, sc1, 3 * D, 2 * D, sc2, SSRC, SSRC);
        gemm(sc2, enc_out_w + (size_t)i * D * D, enc_out_b + (size_t)i * D, sc1, NS, D, D, 0, stream);
        hipLaunchKernelGGL(ln_kernel, dim3(NS), dim3(64), 0, stream,
                           s, sc1, enc_ln1_g + (size_t)i * D, enc_ln1_b + (size_t)i * D, s);
        gemm(s, enc_ff1_w + (size_t)i * DFF_ * D, enc_ff1_b + (size_t)i * DFF_, sc1, NS, DFF_, D, 1, stream);
        gemm(sc1, enc_ff2_w + (size_t)i * D * DFF_, enc_ff2_b + (size_t)i * D, sc2, NS, D, DFF_, 0, stream);
        hipLaunchKernelGGL(ln_kernel, dim3(NS), dim3(64), 0, stream,
                           s, sc2, enc_ln2_g + (size_t)i * D, enc_ln2_b + (size_t)i * D, s);
    }
    hipLaunchKernelGGL(ln_kernel, dim3(NS), dim3(64), 0, stream,
                       s, (const float*)nullptr, enc_norm_g, enc_norm_b, mem);

    // ---------------- Decoder ----------------
    hipLaunchKernelGGL(addpe_kernel, dim3(NT * D / 256), dim3(256), 0, stream, tgt, t);

    for (int i = 0; i < LD; i++) {
        // self-attention
        const float* Wsa = dec_sa_qkv_w + (size_t)i * 3 * D * D;
        const float* bsa = dec_sa_qkv_b + (size_t)i * 3 * D;
        gemm(t, Wsa, bsa, sc1, NT, 3 * D, D, 0, stream);
        hipLaunchKernelGGL((attn_kernel<16>), dim3(B * NH * STGT), dim3(64), 0, stream,
                           sc1, 3 * D, 0, sc1, 3 * D, D, sc1, 3 * D, 2 * D, sc2, STGT, STGT);
        gemm(sc2, dec_sa_out_w + (size_t)i * D * D, dec_sa_out_b + (size_t)i * D, sc1, NT, D, D, 0, stream);
        hipLaunchKernelGGL(ln_kernel, dim3(NT), dim3(64), 0, stream,
                           t, sc1, dec_ln1_g + (size_t)i * D, dec_ln1_b + (size_t)i * D, t);

        // cross-attention: Q from t, K/V from mem
        const float* Wca = dec_ca_qkv_w + (size_t)i * 3 * D * D;
        const float* bca = dec_ca_qkv_b + (size_t)i * 3 * D;
        gemm(t, Wca, bca, sc1, NT, D, D, 0, stream);                       // Q: rows 0..127 of Wqkv
        gemm(mem, Wca + (size_t)D * D, bca + D, sc3, NS, 2 * D, D, 0, stream); // K,V: rows 128..383
        hipLaunchKernelGGL((attn_kernel<1>), dim3(B * NH * STGT), dim3(64), 0, stream,
                           sc1, D, 0, sc3, 2 * D, 0, sc3, 2 * D, D, sc2, STGT, SSRC);
        gemm(sc2, dec_ca_out_w + (size_t)i * D * D, dec_ca_out_b + (size_t)i * D, sc1, NT, D, D, 0, stream);
        hipLaunchKernelGGL(ln_kernel, dim3(NT), dim3(64), 0, stream,
                           t, sc1, dec_ln2_g + (size_t)i * D, dec_ln2_b + (size_t)i * D, t);

        // FFN
        gemm(t, dec_ff1_w + (size_t)i * DFF_ * D, dec_ff1_b + (size_t)i * DFF_, sc1, NT, DFF_, D, 1, stream);
        gemm(sc1, dec_ff2_w + (size_t)i * D * DFF_, dec_ff2_b + (size_t)i * D, sc2, NT, D, DFF_, 0, stream);
        hipLaunchKernelGGL(ln_kernel, dim3(NT), dim3(64), 0, stream,
                           t, sc2, dec_ln3_g + (size_t)i * D, dec_ln3_b + (size_t)i * D, t);
    }

    hipLaunchKernelGGL(ln_kernel, dim3(NT), dim3(64), 0, stream,
                       t, (const float*)nullptr, dec_norm_g, dec_norm_b, sc2);
    hipLaunchKernelGGL(fc_kernel, dim3(NT), dim3(64), 0, stream,
                       sc2, fc_w, fc_b, (float*)d_out);
}

// Round 3
// 4497.009 us; speedup vs baseline: 11.0578x; 11.0578x over previous
//
#include <hip/hip_runtime.h>
#include <hip/hip_bf16.h>

#define NH 8
#define DH 16

// PyTorch-style sinusoidal PE
__device__ __forceinline__ float pe_val(int pos, int d) {
    int j = d >> 1;
    float div = expf((float)j * -0.14391156831212787f);
    float ang = (float)pos * div;
    return (d & 1) ? cosf(ang) : sinf(ang);
}

__global__ void embed_kernel(const int* __restrict__ src, const float* __restrict__ emb,
                             float* __restrict__ S) {
    int idx = blockIdx.x * 256 + threadIdx.x;
    int d = idx & 127;
    int n = idx >> 7;
    int i = n & 63;
    int tok = src[n];
    S[idx] = emb[tok * 128 + d] * 11.313708498984761f + pe_val(i, d);
}

__global__ void addpe_kernel(const float* __restrict__ tgt, float* __restrict__ T) {
    int idx = blockIdx.x * 256 + threadIdx.x;
    int d = idx & 127;
    int n = idx >> 7;
    int i = n & 1023;
    T[idx] = tgt[idx] + pe_val(i, d);
}

// C[m,n] = sum_k A[m,k]*W[n,k] + bias[n], optional ReLU. 64x64 tile, BK=16,
// 256 threads, 4x4 acc/thread. M,N multiples of 64; K multiple of 16.
__global__ __launch_bounds__(256) void gemm64(const float* __restrict__ A,
                                              const float* __restrict__ W,
                                              const float* __restrict__ bias,
                                              float* __restrict__ C,
                                              int M, int N, int K, int relu) {
    __shared__ float As[16][64];   // k-major: As[k][m]
    __shared__ float Ws[16][64];   // k-major: Ws[k][n]
    int tid = threadIdx.x;
    int m0 = blockIdx.y * 64, n0 = blockIdx.x * 64;
    int tn = tid & 15, tm = tid >> 4;     // compute thread grid 16x16
    int lr = tid >> 2, lc = (tid & 3) * 4; // staging: row, k-offset

    const float* Ap = A + (size_t)(m0 + lr) * K + lc;
    const float* Wp = W + (size_t)(n0 + lr) * K + lc;

    float acc[4][4] = {};
    float4 av = *(const float4*)(Ap);
    float4 wv = *(const float4*)(Wp);
    for (int k0 = 0; k0 < K; k0 += 16) {
        __syncthreads();
        As[lc + 0][lr] = av.x; As[lc + 1][lr] = av.y; As[lc + 2][lr] = av.z; As[lc + 3][lr] = av.w;
        Ws[lc + 0][lr] = wv.x; Ws[lc + 1][lr] = wv.y; Ws[lc + 2][lr] = wv.z; Ws[lc + 3][lr] = wv.w;
        __syncthreads();
        if (k0 + 16 < K) {   // prefetch next k-tile; overlaps with compute below
            av = *(const float4*)(Ap + k0 + 16);
            wv = *(const float4*)(Wp + k0 + 16);
        }
#pragma unroll
        for (int k = 0; k < 16; k++) {
            float4 a = *(const float4*)&As[k][tm * 4];
            float4 w = *(const float4*)&Ws[k][tn * 4];
            float ar[4] = {a.x, a.y, a.z, a.w};
            float wr[4] = {w.x, w.y, w.z, w.w};
#pragma unroll
            for (int i = 0; i < 4; i++)
#pragma unroll
                for (int j = 0; j < 4; j++) acc[i][j] += ar[i] * wr[j];
        }
    }
    float4 bv = *(const float4*)(bias + n0 + tn * 4);
    float br[4] = {bv.x, bv.y, bv.z, bv.w};
#pragma unroll
    for (int i = 0; i < 4; i++) {
        float4 out;
        float* o = (float*)&out;
#pragma unroll
        for (int j = 0; j < 4; j++) {
            float v = acc[i][j] + br[j];
            o[j] = relu ? fmaxf(v, 0.f) : v;
        }
        *(float4*)(C + (size_t)(m0 + tm * 4 + i) * N + n0 + tn * 4) = out;
    }
}

// Flash-style attention. One block of BLK threads handles BLK queries of one
// (b,h). Each thread owns one query: online softmax state in registers.
// K/V staged in LDS in 64-row tiles with coalesced float4 loads; LDS reads
// during compute are wave-broadcast (conflict-free). SKV multiple of 64.
template <int BLK>
__global__ __launch_bounds__(BLK) void flash_attn(
    const float* __restrict__ Qb, int qstride, int qoff,
    const float* __restrict__ Kb, int kstride, int koff,
    const float* __restrict__ Vb, int vstride, int voff,
    float* __restrict__ O, int SQ, int SKV) {
    __shared__ float Ks[64][16];
    __shared__ float Vs[64][16];
    int tid = threadIdx.x;
    int nqb = SQ / BLK;
    int bid = blockIdx.x;
    int qb = bid % nqb;
    int h = (bid / nqb) % NH;
    int b = bid / (nqb * NH);
    int q = qb * BLK + tid;

    const float* qp = Qb + (size_t)(b * SQ + q) * qstride + qoff + h * DH;
    float qv[DH];
#pragma unroll
    for (int d = 0; d < DH; d++) qv[d] = qp[d];

    float m = -1e30f, l = 0.f;
    float acc[DH];
#pragma unroll
    for (int d = 0; d < DH; d++) acc[d] = 0.f;

    for (int j0 = 0; j0 < SKV; j0 += 64) {
        __syncthreads();
        for (int idx = tid; idx < 256; idx += BLK) {
            int row = idx >> 2, seg = (idx & 3) * 4;
            size_t krow = (size_t)(b * SKV + j0 + row);
            *((float4*)&Ks[row][seg]) = *(const float4*)(Kb + krow * kstride + koff + h * DH + seg);
            *((float4*)&Vs[row][seg]) = *(const float4*)(Vb + krow * vstride + voff + h * DH + seg);
        }
        __syncthreads();
#pragma unroll 4
        for (int j = 0; j < 64; j++) {
            float s = 0.f;
#pragma unroll
            for (int d = 0; d < DH; d++) s += qv[d] * Ks[j][d];
            s *= 0.25f;  // 1/sqrt(16)
            if (s > m) {  // rare after warm-up; wave-divergent but amortized
                float corr = __expf(m - s);
                l *= corr;
#pragma unroll
                for (int d = 0; d < DH; d++) acc[d] *= corr;
                m = s;
            }
            float p = __expf(s - m);
            l += p;
#pragma unroll
            for (int d = 0; d < DH; d++) acc[d] += p * Vs[j][d];
        }
    }
    float inv = 1.f / l;
    float* op = O + (size_t)(b * SQ + q) * 128 + h * DH;
#pragma unroll
    for (int d = 0; d < DH; d++) op[d] = acc[d] * inv;
}

// Y[r,:] = LN(X[r,:] + R[r,:]) * g + b over 128 cols. One wave per row.
__global__ void ln_kernel(const float* __restrict__ X, const float* __restrict__ R,
                          const float* __restrict__ g, const float* __restrict__ bta,
                          float* __restrict__ Y) {
    int r = blockIdx.x;
    int lane = threadIdx.x;
    size_t base = (size_t)r * 128;
    float x0 = X[base + lane], x1 = X[base + lane + 64];
    if (R) { x0 += R[base + lane]; x1 += R[base + lane + 64]; }
    float s = x0 + x1;
    for (int off = 32; off; off >>= 1) s += __shfl_xor(s, off);
    float mean = s * (1.f / 128.f);
    float d0 = x0 - mean, d1 = x1 - mean;
    float vs = d0 * d0 + d1 * d1;
    for (int off = 32; off; off >>= 1) vs += __shfl_xor(vs, off);
    float rstd = rsqrtf(vs * (1.f / 128.f) + 1e-5f);
    Y[base + lane] = d0 * rstd * g[lane] + bta[lane];
    Y[base + lane + 64] = d1 * rstd * g[lane + 64] + bta[lane + 64];
}

__global__ void fc_kernel(const float* __restrict__ X, const float* __restrict__ w,
                          const float* __restrict__ b, float* __restrict__ out) {
    int r = blockIdx.x;
    int lane = threadIdx.x;
    size_t base = (size_t)r * 128;
    float s = X[base + lane] * w[lane] + X[base + lane + 64] * w[lane + 64];
    for (int off = 32; off; off >>= 1) s += __shfl_xor(s, off);
    if (lane == 0) out[r] = s + b[0];
}

static inline void gemm(const float* A, const float* W, const float* bias, float* C,
                        int M, int N, int K, int relu, hipStream_t st) {
    dim3 g(N / 64, M / 64), blk(256);
    hipLaunchKernelGGL(gemm64, g, blk, 0, st, A, W, bias, C, M, N, K, relu);
}

extern "C" void kernel_launch(void* const* d_in, const int* in_sizes, int n_in,
                              void* d_out, int out_size, void* d_ws, size_t ws_size,
                              hipStream_t stream) {
    const int B = 32, SSRC = 64, STGT = 1024, D = 128, DFF_ = 512, LE = 6, LD = 6;

    const int*   src = (const int*)d_in[0];
    const float* tgt = (const float*)d_in[1];
    const float* emb = (const float*)d_in[2];
    const float* enc_qkv_w = (const float*)d_in[3];
    const float* enc_qkv_b = (const float*)d_in[4];
    const float* enc_out_w = (const float*)d_in[5];
    const float* enc_out_b = (const float*)d_in[6];
    const float* enc_ln1_g = (const float*)d_in[7];
    const float* enc_ln1_b = (const float*)d_in[8];
    const float* enc_ff1_w = (const float*)d_in[9];
    const float* enc_ff1_b = (const float*)d_in[10];
    const float* enc_ff2_w = (const float*)d_in[11];
    const float* enc_ff2_b = (const float*)d_in[12];
    const float* enc_ln2_g = (const float*)d_in[13];
    const float* enc_ln2_b = (const float*)d_in[14];
    const float* enc_norm_g = (const float*)d_in[15];
    const float* enc_norm_b = (const float*)d_in[16];
    const float* dec_sa_qkv_w = (const float*)d_in[17];
    const float* dec_sa_qkv_b = (const float*)d_in[18];
    const float* dec_sa_out_w = (const float*)d_in[19];
    const float* dec_sa_out_b = (const float*)d_in[20];
    const float* dec_ln1_g = (const float*)d_in[21];
    const float* dec_ln1_b = (const float*)d_in[22];
    const float* dec_ca_qkv_w = (const float*)d_in[23];
    const float* dec_ca_qkv_b = (const float*)d_in[24];
    const float* dec_ca_out_w = (const float*)d_in[25];
    const float* dec_ca_out_b = (const float*)d_in[26];
    const float* dec_ln2_g = (const float*)d_in[27];
    const float* dec_ln2_b = (const float*)d_in[28];
    const float* dec_ff1_w = (const float*)d_in[29];
    const float* dec_ff1_b = (const float*)d_in[30];
    const float* dec_ff2_w = (const float*)d_in[31];
    const float* dec_ff2_b = (const float*)d_in[32];
    const float* dec_ln3_g = (const float*)d_in[33];
    const float* dec_ln3_b = (const float*)d_in[34];
    const float* dec_norm_g = (const float*)d_in[35];
    const float* dec_norm_b = (const float*)d_in[36];
    const float* fc_w = (const float*)d_in[37];
    const float* fc_b = (const float*)d_in[38];

    const int NT = B * STGT;   // 32768 decoder rows
    const int NS = B * SSRC;   // 2048 encoder rows

    float* ws = (float*)d_ws;
    float* t   = ws;                      // 32768*128
    float* s   = t + (size_t)NT * D;      // 2048*128
    float* mem = s + (size_t)NS * D;      // 2048*128
    float* sc1 = mem + (size_t)NS * D;    // 32768*512
    float* sc2 = sc1 + (size_t)NT * DFF_; // 32768*128
    float* sc3 = sc2 + (size_t)NT * D;    // 2048*256

    // ---------------- Encoder ----------------
    hipLaunchKernelGGL(embed_kernel, dim3(NS * D / 256), dim3(256), 0, stream, src, emb, s);

    for (int i = 0; i < LE; i++) {
        const float* Wqkv = enc_qkv_w + (size_t)i * 3 * D * D;
        const float* bqkv = enc_qkv_b + (size_t)i * 3 * D;
        gemm(s, Wqkv, bqkv, sc1, NS, 3 * D, D, 0, stream);
        hipLaunchKernelGGL((flash_attn<64>), dim3(B * NH), dim3(64), 0, stream,
                           sc1, 3 * D, 0, sc1, 3 * D, D, sc1, 3 * D, 2 * D, sc2, SSRC, SSRC);
        gemm(sc2, enc_out_w + (size_t)i * D * D, enc_out_b + (size_t)i * D, sc1, NS, D, D, 0, stream);
        hipLaunchKernelGGL(ln_kernel, dim3(NS), dim3(64), 0, stream,
                           s, sc1, enc_ln1_g + (size_t)i * D, enc_ln1_b + (size_t)i * D, s);
        gemm(s, enc_ff1_w + (size_t)i * DFF_ * D, enc_ff1_b + (size_t)i * DFF_, sc1, NS, DFF_, D, 1, stream);
        gemm(sc1, enc_ff2_w + (size_t)i * D * DFF_, enc_ff2_b + (size_t)i * D, sc2, NS, D, DFF_, 0, stream);
        hipLaunchKernelGGL(ln_kernel, dim3(NS), dim3(64), 0, stream,
                           s, sc2, enc_ln2_g + (size_t)i * D, enc_ln2_b + (size_t)i * D, s);
    }
    hipLaunchKernelGGL(ln_kernel, dim3(NS), dim3(64), 0, stream,
                       s, (const float*)nullptr, enc_norm_g, enc_norm_b, mem);

    // ---------------- Decoder ----------------
    hipLaunchKernelGGL(addpe_kernel, dim3(NT * D / 256), dim3(256), 0, stream, tgt, t);

    for (int i = 0; i < LD; i++) {
        // self-attention
        const float* Wsa = dec_sa_qkv_w + (size_t)i * 3 * D * D;
        const float* bsa = dec_sa_qkv_b + (size_t)i * 3 * D;
        gemm(t, Wsa, bsa, sc1, NT, 3 * D, D, 0, stream);
        hipLaunchKernelGGL((flash_attn<256>), dim3(B * NH * (STGT / 256)), dim3(256), 0, stream,
                           sc1, 3 * D, 0, sc1, 3 * D, D, sc1, 3 * D, 2 * D, sc2, STGT, STGT);
        gemm(sc2, dec_sa_out_w + (size_t)i * D * D, dec_sa_out_b + (size_t)i * D, sc1, NT, D, D, 0, stream);
        hipLaunchKernelGGL(ln_kernel, dim3(NT), dim3(64), 0, stream,
                           t, sc1, dec_ln1_g + (size_t)i * D, dec_ln1_b + (size_t)i * D, t);

        // cross-attention: Q from t, K/V from mem
        const float* Wca = dec_ca_qkv_w + (size_t)i * 3 * D * D;
        const float* bca = dec_ca_qkv_b + (size_t)i * 3 * D;
        gemm(t, Wca, bca, sc1, NT, D, D, 0, stream);
        gemm(mem, Wca + (size_t)D * D, bca + D, sc3, NS, 2 * D, D, 0, stream);
        hipLaunchKernelGGL((flash_attn<256>), dim3(B * NH * (STGT / 256)), dim3(256), 0, stream,
                           sc1, D, 0, sc3, 2 * D, 0, sc3, 2 * D, D, sc2, STGT, SSRC);
        gemm(sc2, dec_ca_out_w + (size_t)i * D * D, dec_ca_out_b + (size_t)i * D, sc1, NT, D, D, 0, stream);
        hipLaunchKernelGGL(ln_kernel, dim3(NT), dim3(64), 0, stream,
                           t, sc1, dec_ln2_g + (size_t)i * D, dec_ln2_b + (size_t)i * D, t);

        // FFN
        gemm(t, dec_ff1_w + (size_t)i * DFF_ * D, dec_ff1_b + (size_t)i * DFF_, sc1, NT, DFF_, D, 1, stream);
        gemm(sc1, dec_ff2_w + (size_t)i * D * DFF_, dec_ff2_b + (size_t)i * D, sc2, NT, D, DFF_, 0, stream);
        hipLaunchKernelGGL(ln_kernel, dim3(NT), dim3(64), 0, stream,
                           t, sc2, dec_ln3_g + (size_t)i * D, dec_ln3_b + (size_t)i * D, t);
    }

    hipLaunchKernelGGL(ln_kernel, dim3(NT), dim3(64), 0, stream,
                       t, (const float*)nullptr, dec_norm_g, dec_norm_b, sc2);
    hipLaunchKernelGGL(fc_kernel, dim3(NT), dim3(64), 0, stream,
                       sc2, fc_w, fc_b, (float*)d_out);
}

// Round 4
// 1803.452 us; speedup vs baseline: 27.5733x; 2.4936x over previous
//
#include <hip/hip_runtime.h>
#include <hip/hip_bf16.h>
#include <stdint.h>

#define NH 8

typedef uint16_t u16;
typedef __attribute__((ext_vector_type(8))) short s8b;    // 8 bf16 (4 VGPR)
typedef __attribute__((ext_vector_type(4))) float f32x4;
typedef __attribute__((ext_vector_type(16))) float f32x16;

// fp32 -> bf16 round-to-nearest-even
__device__ __forceinline__ u16 f2b(float f) {
    uint32_t u = __builtin_bit_cast(uint32_t, f);
    u = (u + 0x7fffu + ((u >> 16) & 1u)) >> 16;
    return (u16)u;
}
__device__ __forceinline__ void stv(float* p, float v) { *p = v; }
__device__ __forceinline__ void stv(u16* p, float v) { *p = f2b(v); }

// PyTorch-style sinusoidal PE
__device__ __forceinline__ float pe_val(int pos, int d) {
    int j = d >> 1;
    float div = expf((float)j * -0.14391156831212787f);
    float ang = (float)pos * div;
    return (d & 1) ? cosf(ang) : sinf(ang);
}

__global__ void embed_kernel(const int* __restrict__ src, const float* __restrict__ emb,
                             float* __restrict__ S, u16* __restrict__ Sb) {
    int idx = blockIdx.x * 256 + threadIdx.x;
    int d = idx & 127;
    int n = idx >> 7;
    int i = n & 63;
    int tok = src[n];
    float v = emb[tok * 128 + d] * 11.313708498984761f + pe_val(i, d);
    S[idx] = v; Sb[idx] = f2b(v);
}

__global__ void addpe_kernel(const float* __restrict__ tgt, float* __restrict__ T,
                             u16* __restrict__ Tb) {
    int idx = blockIdx.x * 256 + threadIdx.x;
    int d = idx & 127;
    int n = idx >> 7;
    int i = n & 1023;
    float v = tgt[idx] + pe_val(i, d);
    T[idx] = v; Tb[idx] = f2b(v);
}

// Batched fp32->bf16 weight conversion (one launch, blockIdx.y = tensor index)
struct CvtJobs { const float* src[10]; u16* dst[10]; int n[10]; };
__global__ void cvt_kernel(CvtJobs jb) {
    int e = blockIdx.y;
    int i = blockIdx.x * 256 + threadIdx.x;
    if (i < jb.n[e]) jb.dst[e][i] = f2b(jb.src[e][i]);
}

// C[m,n] = sum_k A[m,k]*W[n,k] + bias[n]; A,W bf16, fp32 accum via MFMA.
// 128x128 block tile, 4 waves, each wave 64x64 (4x4 of 16x16x32).
// LDS rows padded to 56 elems (112 B): 2-way bank aliasing on frag reads (free).
// M,N multiples of 128; K multiple of 32.
template <typename OutT, int RELU>
__global__ __launch_bounds__(256) void gemm_mfma(const u16* __restrict__ A,
                                                 const u16* __restrict__ W,
                                                 const float* __restrict__ bias,
                                                 OutT* __restrict__ C,
                                                 int M, int N, int K) {
    __shared__ __align__(16) u16 As[128 * 56];
    __shared__ __align__(16) u16 Bs[128 * 56];
    int tid = threadIdx.x;
    int lane = tid & 63, w = tid >> 6;
    int quad = lane >> 4, l15 = lane & 15;
    int m0 = blockIdx.y * 128, n0 = blockIdx.x * 128;
    int wm = (w & 1) * 64, wn = (w >> 1) * 64;
    int srow = tid >> 1, skof = (tid & 1) * 16;

    f32x4 acc[4][4];
#pragma unroll
    for (int i = 0; i < 4; i++)
#pragma unroll
        for (int j = 0; j < 4; j++)
#pragma unroll
            for (int r = 0; r < 4; r++) acc[i][j][r] = 0.f;

    for (int k0 = 0; k0 < K; k0 += 32) {
        const u16* ga = A + (size_t)(m0 + srow) * K + k0 + skof;
        const u16* gw = W + (size_t)(n0 + srow) * K + k0 + skof;
        s8b a0 = *(const s8b*)ga, a1 = *(const s8b*)(ga + 8);
        s8b w0 = *(const s8b*)gw, w1 = *(const s8b*)(gw + 8);
        __syncthreads();
        *(s8b*)(As + srow * 56 + skof) = a0;
        *(s8b*)(As + srow * 56 + skof + 8) = a1;
        *(s8b*)(Bs + srow * 56 + skof) = w0;
        *(s8b*)(Bs + srow * 56 + skof + 8) = w1;
        __syncthreads();
        s8b af[4], bfr[4];
#pragma unroll
        for (int i = 0; i < 4; i++) af[i] = *(const s8b*)(As + (wm + 16 * i + l15) * 56 + quad * 8);
#pragma unroll
        for (int j = 0; j < 4; j++) bfr[j] = *(const s8b*)(Bs + (wn + 16 * j + l15) * 56 + quad * 8);
#pragma unroll
        for (int i = 0; i < 4; i++)
#pragma unroll
            for (int j = 0; j < 4; j++)
                acc[i][j] = __builtin_amdgcn_mfma_f32_16x16x32_bf16(af[i], bfr[j], acc[i][j], 0, 0, 0);
    }
    // epilogue: C/D layout col=lane&15, row=quad*4+reg
#pragma unroll
    for (int j = 0; j < 4; j++) {
        int col = n0 + wn + 16 * j + l15;
        float bv = bias[col];
#pragma unroll
        for (int i = 0; i < 4; i++) {
            int rbase = m0 + wm + 16 * i + quad * 4;
#pragma unroll
            for (int r = 0; r < 4; r++) {
                float v = acc[i][j][r] + bv;
                if (RELU) v = fmaxf(v, 0.f);
                stv(C + (size_t)(rbase + r) * N + col, v);
            }
        }
    }
}

// MFMA flash attention, DH=16, head h. One wave = 32 queries; block = WAVES waves
// of the same (b,h). K-tiles of 32 keys. Fixed-max softmax (scores are O(1) with
// these weights; exp cannot overflow), row-sums accumulated via P*ones MFMA so
// normalization needs no shuffles/LDS.
// QK^T: one v_mfma_f32_32x32x16_bf16 (A=Q frag, B=K frag, both 16B contiguous).
// PV + P*ones: v_mfma_f32_16x16x32_bf16 pairs; P goes C-layout -> LDS -> A-layout.
template <int WAVES>
__global__ __launch_bounds__(WAVES * 64) void attn_mfma(
    const u16* __restrict__ Qb, int qstride, int qoff,
    const u16* __restrict__ KVb, int kvstride, int koff, int voff,
    u16* __restrict__ O, int SQ, int SKV) {
    __shared__ __align__(16) u16 Vt[16 * 56];            // V^T tile, padded rows
    __shared__ __align__(16) u16 Ps[WAVES][32 * 56];     // per-wave P tile
    int tid = threadIdx.x;
    int lane = tid & 63, w = tid >> 6;
    int quad = lane >> 4, l15 = lane & 15, l31 = lane & 31, half = lane >> 5;
    int nqc = SQ / (WAVES * 32);
    int bid = blockIdx.x;
    int qc = bid % nqc;
    int h = (bid / nqc) % NH;
    int b = bid / (nqc * NH);
    int q0 = qc * WAVES * 32 + w * 32;

    // Q fragment: A[q=lane&31][k=8*half+j] -> 16B from Q row
    const u16* qp = Qb + (size_t)(b * SQ + q0 + l31) * qstride + qoff + h * 16 + half * 8;
    s8b qf = *(const s8b*)qp;
    s8b ones;
#pragma unroll
    for (int j = 0; j < 8; j++) ones[j] = (short)0x3F80;  // bf16 1.0

    f32x4 O0, O1, L0, L1;
#pragma unroll
    for (int r = 0; r < 4; r++) { O0[r] = 0.f; O1[r] = 0.f; L0[r] = 0.f; L1[r] = 0.f; }

    for (int j0 = 0; j0 < SKV; j0 += 32) {
        __syncthreads();
        // stage V^T tile: Vt[n][k] = V[j0+k][n]
        for (int e = tid; e < 512; e += WAVES * 64) {
            int k = e >> 4, n = e & 15;
            Vt[n * 56 + k] = KVb[(size_t)(b * SKV + j0 + k) * kvstride + voff + h * 16 + n];
        }
        __syncthreads();
        // K fragment: B[k=8*half+j][key=lane&31] = K[key][k-range] -> 16B from K row
        const u16* kp = KVb + (size_t)(b * SKV + j0 + l31) * kvstride + koff + h * 16 + half * 8;
        s8b kf = *(const s8b*)kp;
        f32x16 S;
#pragma unroll
        for (int r = 0; r < 16; r++) S[r] = 0.f;
        S = __builtin_amdgcn_mfma_f32_32x32x16_bf16(qf, kf, S, 0, 0, 0);
        // p = exp(s/4); write to LDS in (row,col) from 32x32 C-layout:
        // col = lane&31, row = (r&3) + 8*(r>>2) + 4*half
        u16* pw = Ps[w];
#pragma unroll
        for (int r = 0; r < 16; r++) {
            float p = __expf(S[r] * 0.25f);
            int row = (r & 3) + 8 * (r >> 2) + 4 * half;
            pw[row * 56 + l31] = f2b(p);
        }
        __builtin_amdgcn_wave_barrier();  // same-wave LDS RAW: in-order LDS pipe + sched fence
        s8b pa0 = *(const s8b*)(pw + l15 * 56 + quad * 8);
        s8b pa1 = *(const s8b*)(pw + (16 + l15) * 56 + quad * 8);
        s8b vb = *(const s8b*)(Vt + l15 * 56 + quad * 8);
        O0 = __builtin_amdgcn_mfma_f32_16x16x32_bf16(pa0, vb, O0, 0, 0, 0);
        O1 = __builtin_amdgcn_mfma_f32_16x16x32_bf16(pa1, vb, O1, 0, 0, 0);
        L0 = __builtin_amdgcn_mfma_f32_16x16x32_bf16(pa0, ones, L0, 0, 0, 0);
        L1 = __builtin_amdgcn_mfma_f32_16x16x32_bf16(pa1, ones, L1, 0, 0, 0);
    }
    // O row = quad*4+r (+16 for frag1), col = lane&15; L holds matching row-sums
#pragma unroll
    for (int r = 0; r < 4; r++) {
        int q = b * SQ + q0 + quad * 4 + r;
        O[(size_t)q * 128 + h * 16 + l15] = f2b(O0[r] / L0[r]);
        O[(size_t)(q + 16) * 128 + h * 16 + l15] = f2b(O1[r] / L1[r]);
    }
}

// Y[r,:] = LN(X[r,:] + R[r,:]) * g + b over 128 cols; optional bf16 copy.
__global__ void ln_kernel(const float* __restrict__ X, const float* __restrict__ R,
                          const float* __restrict__ g, const float* __restrict__ bta,
                          float* __restrict__ Y, u16* __restrict__ Yb) {
    int r = blockIdx.x;
    int lane = threadIdx.x;
    size_t base = (size_t)r * 128;
    float x0 = X[base + lane], x1 = X[base + lane + 64];
    if (R) { x0 += R[base + lane]; x1 += R[base + lane + 64]; }
    float s = x0 + x1;
    for (int off = 32; off; off >>= 1) s += __shfl_xor(s, off);
    float mean = s * (1.f / 128.f);
    float d0 = x0 - mean, d1 = x1 - mean;
    float vs = d0 * d0 + d1 * d1;
    for (int off = 32; off; off >>= 1) vs += __shfl_xor(vs, off);
    float rstd = rsqrtf(vs * (1.f / 128.f) + 1e-5f);
    float y0 = d0 * rstd * g[lane] + bta[lane];
    float y1 = d1 * rstd * g[lane + 64] + bta[lane + 64];
    Y[base + lane] = y0;
    Y[base + lane + 64] = y1;
    if (Yb) { Yb[base + lane] = f2b(y0); Yb[base + lane + 64] = f2b(y1); }
}

__global__ void fc_kernel(const float* __restrict__ X, const float* __restrict__ w,
                          const float* __restrict__ b, float* __restrict__ out) {
    int r = blockIdx.x;
    int lane = threadIdx.x;
    size_t base = (size_t)r * 128;
    float s = X[base + lane] * w[lane] + X[base + lane + 64] * w[lane + 64];
    for (int off = 32; off; off >>= 1) s += __shfl_xor(s, off);
    if (lane == 0) out[r] = s + b[0];
}

static inline void gemm_f(const u16* A, const u16* W, const float* bias, float* C,
                          int M, int N, int K, hipStream_t st) {
    hipLaunchKernelGGL((gemm_mfma<float, 0>), dim3(N / 128, M / 128), dim3(256), 0, st,
                       A, W, bias, C, M, N, K);
}
static inline void gemm_b(const u16* A, const u16* W, const float* bias, u16* C,
                          int M, int N, int K, hipStream_t st) {
    hipLaunchKernelGGL((gemm_mfma<u16, 0>), dim3(N / 128, M / 128), dim3(256), 0, st,
                       A, W, bias, C, M, N, K);
}
static inline void gemm_br(const u16* A, const u16* W, const float* bias, u16* C,
                           int M, int N, int K, hipStream_t st) {
    hipLaunchKernelGGL((gemm_mfma<u16, 1>), dim3(N / 128, M / 128), dim3(256), 0, st,
                       A, W, bias, C, M, N, K);
}

extern "C" void kernel_launch(void* const* d_in, const int* in_sizes, int n_in,
                              void* d_out, int out_size, void* d_ws, size_t ws_size,
                              hipStream_t stream) {
    const int B = 32, SSRC = 64, STGT = 1024, D = 128, DFF_ = 512, LE = 6, LD = 6;

    const int*   src = (const int*)d_in[0];
    const float* tgt = (const float*)d_in[1];
    const float* emb = (const float*)d_in[2];
    const float* enc_qkv_w = (const float*)d_in[3];
    const float* enc_qkv_b = (const float*)d_in[4];
    const float* enc_out_w = (const float*)d_in[5];
    const float* enc_out_b = (const float*)d_in[6];
    const float* enc_ln1_g = (const float*)d_in[7];
    const float* enc_ln1_b = (const float*)d_in[8];
    const float* enc_ff1_w = (const float*)d_in[9];
    const float* enc_ff1_b = (const float*)d_in[10];
    const float* enc_ff2_w = (const float*)d_in[11];
    const float* enc_ff2_b = (const float*)d_in[12];
    const float* enc_ln2_g = (const float*)d_in[13];
    const float* enc_ln2_b = (const float*)d_in[14];
    const float* enc_norm_g = (const float*)d_in[15];
    const float* enc_norm_b = (const float*)d_in[16];
    const float* dec_sa_qkv_w = (const float*)d_in[17];
    const float* dec_sa_qkv_b = (const float*)d_in[18];
    const float* dec_sa_out_w = (const float*)d_in[19];
    const float* dec_sa_out_b = (const float*)d_in[20];
    const float* dec_ln1_g = (const float*)d_in[21];
    const float* dec_ln1_b = (const float*)d_in[22];
    const float* dec_ca_qkv_w = (const float*)d_in[23];
    const float* dec_ca_qkv_b = (const float*)d_in[24];
    const float* dec_ca_out_w = (const float*)d_in[25];
    const float* dec_ca_out_b = (const float*)d_in[26];
    const float* dec_ln2_g = (const float*)d_in[27];
    const float* dec_ln2_b = (const float*)d_in[28];
    const float* dec_ff1_w = (const float*)d_in[29];
    const float* dec_ff1_b = (const float*)d_in[30];
    const float* dec_ff2_w = (const float*)d_in[31];
    const float* dec_ff2_b = (const float*)d_in[32];
    const float* dec_ln3_g = (const float*)d_in[33];
    const float* dec_ln3_b = (const float*)d_in[34];
    const float* dec_norm_g = (const float*)d_in[35];
    const float* dec_norm_b = (const float*)d_in[36];
    const float* fc_w = (const float*)d_in[37];
    const float* fc_b = (const float*)d_in[38];

    const int NT = B * STGT;   // 32768
    const int NS = B * SSRC;   // 2048

    // ---- workspace layout (fp32 region then bf16 region) ----
    float* t_f   = (float*)d_ws;                 // 32768*128
    float* s_f   = t_f + (size_t)NT * D;         // 2048*128
    float* mem_f = s_f + (size_t)NS * D;         // 2048*128
    float* scf   = mem_f + (size_t)NS * D;       // 32768*128 (fp32 proj out / final LN)
    u16* t_bf    = (u16*)(scf + (size_t)NT * D);
    u16* s_bf    = t_bf + (size_t)NT * D;
    u16* mem_bf  = s_bf + (size_t)NS * D;
    u16* qkv_bf  = mem_bf + (size_t)NS * D;      // 32768*512 (qkv / ffn hidden / cross-Q)
    u16* attno_bf = qkv_bf + (size_t)NT * DFF_;  // 32768*128
    u16* ckv_bf  = attno_bf + (size_t)NT * D;    // 2048*256
    u16* wa      = ckv_bf + (size_t)NS * 2 * D;  // weight arena (2,752,512)

    u16* w_enc_qkv = wa;                          int n_enc_qkv = LE * 3 * D * D;
    u16* w_enc_out = w_enc_qkv + n_enc_qkv;       int n_enc_out = LE * D * D;
    u16* w_enc_ff1 = w_enc_out + n_enc_out;       int n_enc_ff1 = LE * DFF_ * D;
    u16* w_enc_ff2 = w_enc_ff1 + n_enc_ff1;       int n_enc_ff2 = LE * D * DFF_;
    u16* w_sa_qkv  = w_enc_ff2 + n_enc_ff2;       int n_sa_qkv = LD * 3 * D * D;
    u16* w_sa_out  = w_sa_qkv + n_sa_qkv;         int n_sa_out = LD * D * D;
    u16* w_ca_qkv  = w_sa_out + n_sa_out;         int n_ca_qkv = LD * 3 * D * D;
    u16* w_ca_out  = w_ca_qkv + n_ca_qkv;         int n_ca_out = LD * D * D;
    u16* w_ff1     = w_ca_out + n_ca_out;         int n_ff1 = LD * DFF_ * D;
    u16* w_ff2     = w_ff1 + n_ff1;               int n_ff2 = LD * D * DFF_;

    // ---- weight conversion (single batched launch) ----
    CvtJobs jb;
    jb.src[0] = enc_qkv_w;   jb.dst[0] = w_enc_qkv; jb.n[0] = n_enc_qkv;
    jb.src[1] = enc_out_w;   jb.dst[1] = w_enc_out; jb.n[1] = n_enc_out;
    jb.src[2] = enc_ff1_w;   jb.dst[2] = w_enc_ff1; jb.n[2] = n_enc_ff1;
    jb.src[3] = enc_ff2_w;   jb.dst[3] = w_enc_ff2; jb.n[3] = n_enc_ff2;
    jb.src[4] = dec_sa_qkv_w; jb.dst[4] = w_sa_qkv; jb.n[4] = n_sa_qkv;
    jb.src[5] = dec_sa_out_w; jb.dst[5] = w_sa_out; jb.n[5] = n_sa_out;
    jb.src[6] = dec_ca_qkv_w; jb.dst[6] = w_ca_qkv; jb.n[6] = n_ca_qkv;
    jb.src[7] = dec_ca_out_w; jb.dst[7] = w_ca_out; jb.n[7] = n_ca_out;
    jb.src[8] = dec_ff1_w;   jb.dst[8] = w_ff1;    jb.n[8] = n_ff1;
    jb.src[9] = dec_ff2_w;   jb.dst[9] = w_ff2;    jb.n[9] = n_ff2;
    int maxn = n_enc_ff1;  // 393216 = largest
    hipLaunchKernelGGL(cvt_kernel, dim3((maxn + 255) / 256, 10), dim3(256), 0, stream, jb);

    // ---------------- Encoder ----------------
    hipLaunchKernelGGL(embed_kernel, dim3(NS * D / 256), dim3(256), 0, stream, src, emb, s_f, s_bf);

    for (int i = 0; i < LE; i++) {
        gemm_b(s_bf, w_enc_qkv + (size_t)i * 3 * D * D, enc_qkv_b + (size_t)i * 3 * D,
               qkv_bf, NS, 3 * D, D, stream);
        hipLaunchKernelGGL((attn_mfma<2>), dim3(B * NH), dim3(128), 0, stream,
                           qkv_bf, 3 * D, 0, qkv_bf, 3 * D, D, 2 * D, attno_bf, SSRC, SSRC);
        gemm_f(attno_bf, w_enc_out + (size_t)i * D * D, enc_out_b + (size_t)i * D,
               scf, NS, D, D, stream);
        hipLaunchKernelGGL(ln_kernel, dim3(NS), dim3(64), 0, stream,
                           s_f, scf, enc_ln1_g + (size_t)i * D, enc_ln1_b + (size_t)i * D, s_f, s_bf);
        gemm_br(s_bf, w_enc_ff1 + (size_t)i * DFF_ * D, enc_ff1_b + (size_t)i * DFF_,
                qkv_bf, NS, DFF_, D, stream);
        gemm_f(qkv_bf, w_enc_ff2 + (size_t)i * D * DFF_, enc_ff2_b + (size_t)i * D,
               scf, NS, D, DFF_, stream);
        hipLaunchKernelGGL(ln_kernel, dim3(NS), dim3(64), 0, stream,
                           s_f, scf, enc_ln2_g + (size_t)i * D, enc_ln2_b + (size_t)i * D, s_f, s_bf);
    }
    hipLaunchKernelGGL(ln_kernel, dim3(NS), dim3(64), 0, stream,
                       s_f, (const float*)nullptr, enc_norm_g, enc_norm_b, mem_f, mem_bf);

    // ---------------- Decoder ----------------
    hipLaunchKernelGGL(addpe_kernel, dim3(NT * D / 256), dim3(256), 0, stream, tgt, t_f, t_bf);

    for (int i = 0; i < LD; i++) {
        // self-attention
        gemm_b(t_bf, w_sa_qkv + (size_t)i * 3 * D * D, dec_sa_qkv_b + (size_t)i * 3 * D,
               qkv_bf, NT, 3 * D, D, stream);
        hipLaunchKernelGGL((attn_mfma<4>), dim3(B * NH * (STGT / 128)), dim3(256), 0, stream,
                           qkv_bf, 3 * D, 0, qkv_bf, 3 * D, D, 2 * D, attno_bf, STGT, STGT);
        gemm_f(attno_bf, w_sa_out + (size_t)i * D * D, dec_sa_out_b + (size_t)i * D,
               scf, NT, D, D, stream);
        hipLaunchKernelGGL(ln_kernel, dim3(NT), dim3(64), 0, stream,
                           t_f, scf, dec_ln1_g + (size_t)i * D, dec_ln1_b + (size_t)i * D, t_f, t_bf);

        // cross-attention
        gemm_b(t_bf, w_ca_qkv + (size_t)i * 3 * D * D, dec_ca_qkv_b + (size_t)i * 3 * D,
               qkv_bf, NT, D, D, stream);  // Q only (first 128 rows of Wqkv)
        gemm_b(mem_bf, w_ca_qkv + (size_t)i * 3 * D * D + (size_t)D * D,
               dec_ca_qkv_b + (size_t)i * 3 * D + D, ckv_bf, NS, 2 * D, D, stream);  // K,V
        hipLaunchKernelGGL((attn_mfma<4>), dim3(B * NH * (STGT / 128)), dim3(256), 0, stream,
                           qkv_bf, D, 0, ckv_bf, 2 * D, 0, D, attno_bf, STGT, SSRC);
        gemm_f(attno_bf, w_ca_out + (size_t)i * D * D, dec_ca_out_b + (size_t)i * D,
               scf, NT, D, D, stream);
        hipLaunchKernelGGL(ln_kernel, dim3(NT), dim3(64), 0, stream,
                           t_f, scf, dec_ln2_g + (size_t)i * D, dec_ln2_b + (size_t)i * D, t_f, t_bf);

        // FFN
        gemm_br(t_bf, w_ff1 + (size_t)i * DFF_ * D, dec_ff1_b + (size_t)i * DFF_,
                qkv_bf, NT, DFF_, D, stream);
        gemm_f(qkv_bf, w_ff2 + (size_t)i * D * DFF_, dec_ff2_b + (size_t)i * D,
               scf, NT, D, DFF_, stream);
        hipLaunchKernelGGL(ln_kernel, dim3(NT), dim3(64), 0, stream,
                           t_f, scf, dec_ln3_g + (size_t)i * D, dec_ln3_b + (size_t)i * D, t_f, t_bf);
    }

    hipLaunchKernelGGL(ln_kernel, dim3(NT), dim3(64), 0, stream,
                       t_f, (const float*)nullptr, dec_norm_g, dec_norm_b, scf, (u16*)nullptr);
    hipLaunchKernelGGL(fc_kernel, dim3(NT), dim3(64), 0, stream,
                       scf, fc_w, fc_b, (float*)d_out);
}

// Round 5
// 1562.543 us; speedup vs baseline: 31.8245x; 1.1542x over previous
//
#include <hip/hip_runtime.h>
#include <hip/hip_bf16.h>
#include <stdint.h>

#define NH 8

typedef uint16_t u16;
typedef __attribute__((ext_vector_type(8))) short s8b;    // 8 bf16 (4 VGPR)
typedef __attribute__((ext_vector_type(4))) float f32x4;
typedef __attribute__((ext_vector_type(16))) float f32x16;

// fp32 -> bf16 round-to-nearest-even
__device__ __forceinline__ u16 f2b(float f) {
    uint32_t u = __builtin_bit_cast(uint32_t, f);
    u = (u + 0x7fffu + ((u >> 16) & 1u)) >> 16;
    return (u16)u;
}

// PyTorch-style sinusoidal PE
__device__ __forceinline__ float pe_val(int pos, int d) {
    int j = d >> 1;
    float div = expf((float)j * -0.14391156831212787f);
    float ang = (float)pos * div;
    return (d & 1) ? cosf(ang) : sinf(ang);
}

__global__ void embed_kernel(const int* __restrict__ src, const float* __restrict__ emb,
                             float* __restrict__ S, u16* __restrict__ Sb) {
    int idx = blockIdx.x * 256 + threadIdx.x;
    int d = idx & 127;
    int n = idx >> 7;
    int i = n & 63;
    int tok = src[n];
    float v = emb[tok * 128 + d] * 11.313708498984761f + pe_val(i, d);
    S[idx] = v; Sb[idx] = f2b(v);
}

__global__ void addpe_kernel(const float* __restrict__ tgt, float* __restrict__ T,
                             u16* __restrict__ Tb) {
    int idx = blockIdx.x * 256 + threadIdx.x;
    int d = idx & 127;
    int n = idx >> 7;
    int i = n & 1023;
    float v = tgt[idx] + pe_val(i, d);
    T[idx] = v; Tb[idx] = f2b(v);
}

// Batched fp32->bf16 weight conversion
struct CvtJobs { const float* src[10]; u16* dst[10]; int n[10]; };
__global__ void cvt_kernel(CvtJobs jb) {
    int e = blockIdx.y;
    int i = blockIdx.x * 256 + threadIdx.x;
    if (i < jb.n[e]) jb.dst[e][i] = f2b(jb.src[e][i]);
}

// VT[b][h][n][k] = V[b][k][h*16+n]  (V = columns [voff, voff+128) of KV rows)
__global__ void transposeV(const u16* __restrict__ KV, int stride, int voff,
                           u16* __restrict__ VT, int SKV) {
    int bh = blockIdx.x;          // b*NH + h
    int k0 = blockIdx.y * 64;
    int l = threadIdx.x;          // 64
    int b = bh >> 3, h = bh & 7;
    const u16* p = KV + (size_t)(b * SKV + k0 + l) * stride + voff + h * 16;
    s8b v0 = *(const s8b*)p;
    s8b v1 = *(const s8b*)(p + 8);
    size_t obase = (size_t)bh * 16 * SKV + k0 + l;
#pragma unroll
    for (int n = 0; n < 8; n++) VT[obase + (size_t)n * SKV] = (u16)v0[n];
#pragma unroll
    for (int n = 0; n < 8; n++) VT[obase + (size_t)(n + 8) * SKV] = (u16)v1[n];
}

// C[m,n] = sum_k A[m,k]*W[n,k] + bias[n]; bf16 in, fp32 MFMA accum, bf16 out.
// 128x128 block tile, 4 waves x (64x64). Optional ReLU.
template <int RELU>
__global__ __launch_bounds__(256) void gemm_mfma(const u16* __restrict__ A,
                                                 const u16* __restrict__ W,
                                                 const float* __restrict__ bias,
                                                 u16* __restrict__ C,
                                                 int M, int N, int K) {
    __shared__ __align__(16) u16 As[128 * 56];
    __shared__ __align__(16) u16 Bs[128 * 56];
    int tid = threadIdx.x;
    int lane = tid & 63, w = tid >> 6;
    int quad = lane >> 4, l15 = lane & 15;
    int m0 = blockIdx.y * 128, n0 = blockIdx.x * 128;
    int wm = (w & 1) * 64, wn = (w >> 1) * 64;
    int srow = tid >> 1, skof = (tid & 1) * 16;

    f32x4 acc[4][4];
#pragma unroll
    for (int i = 0; i < 4; i++)
#pragma unroll
        for (int j = 0; j < 4; j++)
#pragma unroll
            for (int r = 0; r < 4; r++) acc[i][j][r] = 0.f;

    for (int k0 = 0; k0 < K; k0 += 32) {
        const u16* ga = A + (size_t)(m0 + srow) * K + k0 + skof;
        const u16* gw = W + (size_t)(n0 + srow) * K + k0 + skof;
        s8b a0 = *(const s8b*)ga, a1 = *(const s8b*)(ga + 8);
        s8b w0 = *(const s8b*)gw, w1 = *(const s8b*)(gw + 8);
        __syncthreads();
        *(s8b*)(As + srow * 56 + skof) = a0;
        *(s8b*)(As + srow * 56 + skof + 8) = a1;
        *(s8b*)(Bs + srow * 56 + skof) = w0;
        *(s8b*)(Bs + srow * 56 + skof + 8) = w1;
        __syncthreads();
        s8b af[4], bfr[4];
#pragma unroll
        for (int i = 0; i < 4; i++) af[i] = *(const s8b*)(As + (wm + 16 * i + l15) * 56 + quad * 8);
#pragma unroll
        for (int j = 0; j < 4; j++) bfr[j] = *(const s8b*)(Bs + (wn + 16 * j + l15) * 56 + quad * 8);
#pragma unroll
        for (int i = 0; i < 4; i++)
#pragma unroll
            for (int j = 0; j < 4; j++)
                acc[i][j] = __builtin_amdgcn_mfma_f32_16x16x32_bf16(af[i], bfr[j], acc[i][j], 0, 0, 0);
    }
#pragma unroll
    for (int j = 0; j < 4; j++) {
        int col = n0 + wn + 16 * j + l15;
        float bv = bias[col];
#pragma unroll
        for (int i = 0; i < 4; i++) {
            int rbase = m0 + wm + 16 * i + quad * 4;
#pragma unroll
            for (int r = 0; r < 4; r++) {
                float v = acc[i][j][r] + bv;
                if (RELU) v = fmaxf(v, 0.f);
                C[(size_t)(rbase + r) * N + col] = f2b(v);
            }
        }
    }
}

// GEMM (N=128) fused with residual-add + LayerNorm.
// Y = LN(X + A@W.T + bias) * g + bta; writes fp32 Y and bf16 Yb.
// Grid: M/128 blocks (blockIdx.x = m-block).
__global__ __launch_bounds__(256) void gemm_ln(const u16* __restrict__ A,
                                               const u16* __restrict__ W,
                                               const float* __restrict__ bias,
                                               const float* __restrict__ X,
                                               const float* __restrict__ g,
                                               const float* __restrict__ bta,
                                               float* __restrict__ Y,
                                               u16* __restrict__ Yb,
                                               int M, int K) {
    __shared__ __align__(16) u16 As[128 * 56];
    __shared__ __align__(16) u16 Bs[128 * 56];
    __shared__ float redS[128][2], redQ[128][2];
    int tid = threadIdx.x;
    int lane = tid & 63, w = tid >> 6;
    int quad = lane >> 4, l15 = lane & 15;
    int m0 = blockIdx.x * 128;
    int wm = (w & 1) * 64, wn = (w >> 1) * 64;
    int srow = tid >> 1, skof = (tid & 1) * 16;

    f32x4 acc[4][4];
#pragma unroll
    for (int i = 0; i < 4; i++)
#pragma unroll
        for (int j = 0; j < 4; j++)
#pragma unroll
            for (int r = 0; r < 4; r++) acc[i][j][r] = 0.f;

    for (int k0 = 0; k0 < K; k0 += 32) {
        const u16* ga = A + (size_t)(m0 + srow) * K + k0 + skof;
        const u16* gw = W + (size_t)srow * K + k0 + skof;
        s8b a0 = *(const s8b*)ga, a1 = *(const s8b*)(ga + 8);
        s8b w0 = *(const s8b*)gw, w1 = *(const s8b*)(gw + 8);
        __syncthreads();
        *(s8b*)(As + srow * 56 + skof) = a0;
        *(s8b*)(As + srow * 56 + skof + 8) = a1;
        *(s8b*)(Bs + srow * 56 + skof) = w0;
        *(s8b*)(Bs + srow * 56 + skof + 8) = w1;
        __syncthreads();
        s8b af[4], bfr[4];
#pragma unroll
        for (int i = 0; i < 4; i++) af[i] = *(const s8b*)(As + (wm + 16 * i + l15) * 56 + quad * 8);
#pragma unroll
        for (int j = 0; j < 4; j++) bfr[j] = *(const s8b*)(Bs + (wn + 16 * j + l15) * 56 + quad * 8);
#pragma unroll
        for (int i = 0; i < 4; i++)
#pragma unroll
            for (int j = 0; j < 4; j++)
                acc[i][j] = __builtin_amdgcn_mfma_f32_16x16x32_bf16(af[i], bfr[j], acc[i][j], 0, 0, 0);
    }

    // epilogue: x = acc + bias + residual; row stats via quad-shuffles + LDS
    float s_[4][4], q_[4][4];
#pragma unroll
    for (int i = 0; i < 4; i++)
#pragma unroll
        for (int r = 0; r < 4; r++) {
            int row = m0 + wm + 16 * i + quad * 4 + r;
            float s = 0.f, q = 0.f;
#pragma unroll
            for (int j = 0; j < 4; j++) {
                int col = wn + 16 * j + l15;
                float x = acc[i][j][r] + bias[col] + X[(size_t)row * 128 + col];
                acc[i][j][r] = x;
                s += x; q += x * x;
            }
#pragma unroll
            for (int off = 1; off < 16; off <<= 1) {
                s += __shfl_xor(s, off);
                q += __shfl_xor(q, off);
            }
            s_[i][r] = s; q_[i][r] = q;
        }
    if (l15 == 0) {
#pragma unroll
        for (int i = 0; i < 4; i++)
#pragma unroll
            for (int r = 0; r < 4; r++) {
                int lrow = wm + 16 * i + quad * 4 + r;
                redS[lrow][wn >> 6] = s_[i][r];
                redQ[lrow][wn >> 6] = q_[i][r];
            }
    }
    __syncthreads();
#pragma unroll
    for (int i = 0; i < 4; i++)
#pragma unroll
        for (int r = 0; r < 4; r++) {
            int lrow = wm + 16 * i + quad * 4 + r;
            int row = m0 + lrow;
            float S2 = redS[lrow][0] + redS[lrow][1];
            float Q2 = redQ[lrow][0] + redQ[lrow][1];
            float mean = S2 * (1.f / 128.f);
            float var = Q2 * (1.f / 128.f) - mean * mean;
            float rstd = rsqrtf(var + 1e-5f);
#pragma unroll
            for (int j = 0; j < 4; j++) {
                int col = wn + 16 * j + l15;
                float y = (acc[i][j][r] - mean) * rstd * g[col] + bta[col];
                Y[(size_t)row * 128 + col] = y;
                Yb[(size_t)row * 128 + col] = f2b(y);
            }
        }
}

// MFMA flash attention with pre-transposed V (VT[b][h][n][k]).
// One wave = 32 queries; no block-level sync in the k-loop (Ps is wave-private,
// V-frag is a direct global b128 load). Fixed-max softmax; row-sums via P*ones.
template <int WAVES>
__global__ __launch_bounds__(WAVES * 64) void attn2(
    const u16* __restrict__ Qb, int qstride, int qoff,
    const u16* __restrict__ Kb, int kstride, int koff,
    const u16* __restrict__ VT,
    u16* __restrict__ O, int SQ, int SKV) {
    __shared__ __align__(16) u16 Ps[WAVES][32 * 56];
    int tid = threadIdx.x;
    int lane = tid & 63, w = tid >> 6;
    int quad = lane >> 4, l15 = lane & 15, l31 = lane & 31, half = lane >> 5;
    int nqc = SQ / (WAVES * 32);
    int bid = blockIdx.x;
    int qc = bid % nqc;
    int h = (bid / nqc) % NH;
    int b = bid / (nqc * NH);
    int q0 = qc * WAVES * 32 + w * 32;

    const u16* qp = Qb + (size_t)(b * SQ + q0 + l31) * qstride + qoff + h * 16 + half * 8;
    s8b qf = *(const s8b*)qp;
    s8b ones;
#pragma unroll
    for (int j = 0; j < 8; j++) ones[j] = (short)0x3F80;  // bf16 1.0

    const u16* vtb = VT + ((size_t)(b * NH + h) * 16 + l15) * SKV + quad * 8;
    const u16* kp = Kb + (size_t)(b * SKV + l31) * kstride + koff + h * 16 + half * 8;
    size_t kadv = (size_t)32 * kstride;

    f32x4 O0, O1, L0, L1;
#pragma unroll
    for (int r = 0; r < 4; r++) { O0[r] = 0.f; O1[r] = 0.f; L0[r] = 0.f; L1[r] = 0.f; }

    u16* pw = Ps[w];
    for (int j0 = 0; j0 < SKV; j0 += 32) {
        s8b kf = *(const s8b*)kp;
        kp += kadv;
        s8b vb = *(const s8b*)(vtb + j0);
        f32x16 S;
#pragma unroll
        for (int r = 0; r < 16; r++) S[r] = 0.f;
        S = __builtin_amdgcn_mfma_f32_32x32x16_bf16(qf, kf, S, 0, 0, 0);
        // 32x32 C-layout: col = lane&31, row = (r&3) + 8*(r>>2) + 4*half
#pragma unroll
        for (int r = 0; r < 16; r++) {
            float p = __expf(S[r] * 0.25f);
            int row = (r & 3) + 8 * (r >> 2) + 4 * half;
            pw[row * 56 + l31] = f2b(p);
        }
        __builtin_amdgcn_wave_barrier();  // wave-private LDS RAW ordering
        s8b pa0 = *(const s8b*)(pw + l15 * 56 + quad * 8);
        s8b pa1 = *(const s8b*)(pw + (16 + l15) * 56 + quad * 8);
        O0 = __builtin_amdgcn_mfma_f32_16x16x32_bf16(pa0, vb, O0, 0, 0, 0);
        O1 = __builtin_amdgcn_mfma_f32_16x16x32_bf16(pa1, vb, O1, 0, 0, 0);
        L0 = __builtin_amdgcn_mfma_f32_16x16x32_bf16(pa0, ones, L0, 0, 0, 0);
        L1 = __builtin_amdgcn_mfma_f32_16x16x32_bf16(pa1, ones, L1, 0, 0, 0);
    }
#pragma unroll
    for (int r = 0; r < 4; r++) {
        int q = b * SQ + q0 + quad * 4 + r;
        O[(size_t)q * 128 + h * 16 + l15] = f2b(O0[r] / L0[r]);
        O[(size_t)(q + 16) * 128 + h * 16 + l15] = f2b(O1[r] / L1[r]);
    }
}

// Standalone LN (used for enc_norm / dec_norm only)
__global__ void ln_kernel(const float* __restrict__ X, const float* __restrict__ R,
                          const float* __restrict__ g, const float* __restrict__ bta,
                          float* __restrict__ Y, u16* __restrict__ Yb) {
    int r = blockIdx.x;
    int lane = threadIdx.x;
    size_t base = (size_t)r * 128;
    float x0 = X[base + lane], x1 = X[base + lane + 64];
    if (R) { x0 += R[base + lane]; x1 += R[base + lane + 64]; }
    float s = x0 + x1;
    for (int off = 32; off; off >>= 1) s += __shfl_xor(s, off);
    float mean = s * (1.f / 128.f);
    float d0 = x0 - mean, d1 = x1 - mean;
    float vs = d0 * d0 + d1 * d1;
    for (int off = 32; off; off >>= 1) vs += __shfl_xor(vs, off);
    float rstd = rsqrtf(vs * (1.f / 128.f) + 1e-5f);
    float y0 = d0 * rstd * g[lane] + bta[lane];
    float y1 = d1 * rstd * g[lane + 64] + bta[lane + 64];
    Y[base + lane] = y0;
    Y[base + lane + 64] = y1;
    if (Yb) { Yb[base + lane] = f2b(y0); Yb[base + lane + 64] = f2b(y1); }
}

__global__ void fc_kernel(const float* __restrict__ X, const float* __restrict__ w,
                          const float* __restrict__ b, float* __restrict__ out) {
    int r = blockIdx.x;
    int lane = threadIdx.x;
    size_t base = (size_t)r * 128;
    float s = X[base + lane] * w[lane] + X[base + lane + 64] * w[lane + 64];
    for (int off = 32; off; off >>= 1) s += __shfl_xor(s, off);
    if (lane == 0) out[r] = s + b[0];
}

static inline void gemm_b(const u16* A, const u16* W, const float* bias, u16* C,
                          int M, int N, int K, hipStream_t st) {
    hipLaunchKernelGGL((gemm_mfma<0>), dim3(N / 128, M / 128), dim3(256), 0, st,
                       A, W, bias, C, M, N, K);
}
static inline void gemm_br(const u16* A, const u16* W, const float* bias, u16* C,
                           int M, int N, int K, hipStream_t st) {
    hipLaunchKernelGGL((gemm_mfma<1>), dim3(N / 128, M / 128), dim3(256), 0, st,
                       A, W, bias, C, M, N, K);
}
static inline void gemmln(const u16* A, const u16* W, const float* bias,
                          const float* X, const float* g, const float* bta,
                          float* Y, u16* Yb, int M, int K, hipStream_t st) {
    hipLaunchKernelGGL(gemm_ln, dim3(M / 128), dim3(256), 0, st,
                       A, W, bias, X, g, bta, Y, Yb, M, K);
}

extern "C" void kernel_launch(void* const* d_in, const int* in_sizes, int n_in,
                              void* d_out, int out_size, void* d_ws, size_t ws_size,
                              hipStream_t stream) {
    const int B = 32, SSRC = 64, STGT = 1024, D = 128, DFF_ = 512, LE = 6, LD = 6;

    const int*   src = (const int*)d_in[0];
    const float* tgt = (const float*)d_in[1];
    const float* emb = (const float*)d_in[2];
    const float* enc_qkv_w = (const float*)d_in[3];
    const float* enc_qkv_b = (const float*)d_in[4];
    const float* enc_out_w = (const float*)d_in[5];
    const float* enc_out_b = (const float*)d_in[6];
    const float* enc_ln1_g = (const float*)d_in[7];
    const float* enc_ln1_b = (const float*)d_in[8];
    const float* enc_ff1_w = (const float*)d_in[9];
    const float* enc_ff1_b = (const float*)d_in[10];
    const float* enc_ff2_w = (const float*)d_in[11];
    const float* enc_ff2_b = (const float*)d_in[12];
    const float* enc_ln2_g = (const float*)d_in[13];
    const float* enc_ln2_b = (const float*)d_in[14];
    const float* enc_norm_g = (const float*)d_in[15];
    const float* enc_norm_b = (const float*)d_in[16];
    const float* dec_sa_qkv_w = (const float*)d_in[17];
    const float* dec_sa_qkv_b = (const float*)d_in[18];
    const float* dec_sa_out_w = (const float*)d_in[19];
    const float* dec_sa_out_b = (const float*)d_in[20];
    const float* dec_ln1_g = (const float*)d_in[21];
    const float* dec_ln1_b = (const float*)d_in[22];
    const float* dec_ca_qkv_w = (const float*)d_in[23];
    const float* dec_ca_qkv_b = (const float*)d_in[24];
    const float* dec_ca_out_w = (const float*)d_in[25];
    const float* dec_ca_out_b = (const float*)d_in[26];
    const float* dec_ln2_g = (const float*)d_in[27];
    const float* dec_ln2_b = (const float*)d_in[28];
    const float* dec_ff1_w = (const float*)d_in[29];
    const float* dec_ff1_b = (const float*)d_in[30];
    const float* dec_ff2_w = (const float*)d_in[31];
    const float* dec_ff2_b = (const float*)d_in[32];
    const float* dec_ln3_g = (const float*)d_in[33];
    const float* dec_ln3_b = (const float*)d_in[34];
    const float* dec_norm_g = (const float*)d_in[35];
    const float* dec_norm_b = (const float*)d_in[36];
    const float* fc_w = (const float*)d_in[37];
    const float* fc_b = (const float*)d_in[38];

    const int NT = B * STGT;   // 32768
    const int NS = B * SSRC;   // 2048

    // ---- workspace layout ----
    float* t_f   = (float*)d_ws;                 // 32768*128 f32
    float* s_f   = t_f + (size_t)NT * D;         // 2048*128
    float* mem_f = s_f + (size_t)NS * D;         // 2048*128
    u16* t_bf    = (u16*)(mem_f + (size_t)NS * D);
    u16* s_bf    = t_bf + (size_t)NT * D;
    u16* mem_bf  = s_bf + (size_t)NS * D;
    u16* qkv_bf  = mem_bf + (size_t)NS * D;      // 32768*512
    u16* attno_bf = qkv_bf + (size_t)NT * DFF_;  // 32768*128
    u16* ckv_bf  = attno_bf + (size_t)NT * D;    // 2048*256
    u16* vt      = ckv_bf + (size_t)NS * 2 * D;  // B*NH*16*1024 (also reused for SKV=64)
    u16* wa      = vt + (size_t)B * NH * 16 * STGT;

    u16* w_enc_qkv = wa;                          int n_enc_qkv = LE * 3 * D * D;
    u16* w_enc_out = w_enc_qkv + n_enc_qkv;       int n_enc_out = LE * D * D;
    u16* w_enc_ff1 = w_enc_out + n_enc_out;       int n_enc_ff1 = LE * DFF_ * D;
    u16* w_enc_ff2 = w_enc_ff1 + n_enc_ff1;       int n_enc_ff2 = LE * D * DFF_;
    u16* w_sa_qkv  = w_enc_ff2 + n_enc_ff2;       int n_sa_qkv = LD * 3 * D * D;
    u16* w_sa_out  = w_sa_qkv + n_sa_qkv;         int n_sa_out = LD * D * D;
    u16* w_ca_qkv  = w_sa_out + n_sa_out;         int n_ca_qkv = LD * 3 * D * D;
    u16* w_ca_out  = w_ca_qkv + n_ca_qkv;         int n_ca_out = LD * D * D;
    u16* w_ff1     = w_ca_out + n_ca_out;         int n_ff1 = LD * DFF_ * D;
    u16* w_ff2     = w_ff1 + n_ff1;               int n_ff2 = LD * D * DFF_;

    // final-LN fp32 scratch aliases qkv_bf (dead by then)
    float* scf = (float*)qkv_bf;

    // ---- weight conversion ----
    CvtJobs jb;
    jb.src[0] = enc_qkv_w;    jb.dst[0] = w_enc_qkv; jb.n[0] = n_enc_qkv;
    jb.src[1] = enc_out_w;    jb.dst[1] = w_enc_out; jb.n[1] = n_enc_out;
    jb.src[2] = enc_ff1_w;    jb.dst[2] = w_enc_ff1; jb.n[2] = n_enc_ff1;
    jb.src[3] = enc_ff2_w;    jb.dst[3] = w_enc_ff2; jb.n[3] = n_enc_ff2;
    jb.src[4] = dec_sa_qkv_w; jb.dst[4] = w_sa_qkv;  jb.n[4] = n_sa_qkv;
    jb.src[5] = dec_sa_out_w; jb.dst[5] = w_sa_out;  jb.n[5] = n_sa_out;
    jb.src[6] = dec_ca_qkv_w; jb.dst[6] = w_ca_qkv;  jb.n[6] = n_ca_qkv;
    jb.src[7] = dec_ca_out_w; jb.dst[7] = w_ca_out;  jb.n[7] = n_ca_out;
    jb.src[8] = dec_ff1_w;    jb.dst[8] = w_ff1;     jb.n[8] = n_ff1;
    jb.src[9] = dec_ff2_w;    jb.dst[9] = w_ff2;     jb.n[9] = n_ff2;
    int maxn = n_enc_ff1;
    hipLaunchKernelGGL(cvt_kernel, dim3((maxn + 255) / 256, 10), dim3(256), 0, stream, jb);

    // ---------------- Encoder ----------------
    hipLaunchKernelGGL(embed_kernel, dim3(NS * D / 256), dim3(256), 0, stream, src, emb, s_f, s_bf);

    for (int i = 0; i < LE; i++) {
        gemm_b(s_bf, w_enc_qkv + (size_t)i * 3 * D * D, enc_qkv_b + (size_t)i * 3 * D,
               qkv_bf, NS, 3 * D, D, stream);
        hipLaunchKernelGGL(transposeV, dim3(B * NH, 1), dim3(64), 0, stream,
                           qkv_bf, 3 * D, 2 * D, vt, SSRC);
        hipLaunchKernelGGL((attn2<2>), dim3(B * NH), dim3(128), 0, stream,
                           qkv_bf, 3 * D, 0, qkv_bf, 3 * D, D, vt, attno_bf, SSRC, SSRC);
        gemmln(attno_bf, w_enc_out + (size_t)i * D * D, enc_out_b + (size_t)i * D,
               s_f, enc_ln1_g + (size_t)i * D, enc_ln1_b + (size_t)i * D, s_f, s_bf, NS, D, stream);
        gemm_br(s_bf, w_enc_ff1 + (size_t)i * DFF_ * D, enc_ff1_b + (size_t)i * DFF_,
                qkv_bf, NS, DFF_, D, stream);
        gemmln(qkv_bf, w_enc_ff2 + (size_t)i * D * DFF_, enc_ff2_b + (size_t)i * D,
               s_f, enc_ln2_g + (size_t)i * D, enc_ln2_b + (size_t)i * D, s_f, s_bf, NS, DFF_, stream);
    }
    hipLaunchKernelGGL(ln_kernel, dim3(NS), dim3(64), 0, stream,
                       s_f, (const float*)nullptr, enc_norm_g, enc_norm_b, mem_f, mem_bf);

    // ---------------- Decoder ----------------
    hipLaunchKernelGGL(addpe_kernel, dim3(NT * D / 256), dim3(256), 0, stream, tgt, t_f, t_bf);

    for (int i = 0; i < LD; i++) {
        // self-attention
        gemm_b(t_bf, w_sa_qkv + (size_t)i * 3 * D * D, dec_sa_qkv_b + (size_t)i * 3 * D,
               qkv_bf, NT, 3 * D, D, stream);
        hipLaunchKernelGGL(transposeV, dim3(B * NH, STGT / 64), dim3(64), 0, stream,
                           qkv_bf, 3 * D, 2 * D, vt, STGT);
        hipLaunchKernelGGL((attn2<4>), dim3(B * NH * (STGT / 128)), dim3(256), 0, stream,
                           qkv_bf, 3 * D, 0, qkv_bf, 3 * D, D, vt, attno_bf, STGT, STGT);
        gemmln(attno_bf, w_sa_out + (size_t)i * D * D, dec_sa_out_b + (size_t)i * D,
               t_f, dec_ln1_g + (size_t)i * D, dec_ln1_b + (size_t)i * D, t_f, t_bf, NT, D, stream);

        // cross-attention
        gemm_b(t_bf, w_ca_qkv + (size_t)i * 3 * D * D, dec_ca_qkv_b + (size_t)i * 3 * D,
               qkv_bf, NT, D, D, stream);  // Q only
        gemm_b(mem_bf, w_ca_qkv + (size_t)i * 3 * D * D + (size_t)D * D,
               dec_ca_qkv_b + (size_t)i * 3 * D + D, ckv_bf, NS, 2 * D, D, stream);  // K,V
        hipLaunchKernelGGL(transposeV, dim3(B * NH, 1), dim3(64), 0, stream,
                           ckv_bf, 2 * D, D, vt, SSRC);
        hipLaunchKernelGGL((attn2<4>), dim3(B * NH * (STGT / 128)), dim3(256), 0, stream,
                           qkv_bf, D, 0, ckv_bf, 2 * D, 0, vt, attno_bf, STGT, SSRC);
        gemmln(attno_bf, w_ca_out + (size_t)i * D * D, dec_ca_out_b + (size_t)i * D,
               t_f, dec_ln2_g + (size_t)i * D, dec_ln2_b + (size_t)i * D, t_f, t_bf, NT, D, stream);

        // FFN
        gemm_br(t_bf, w_ff1 + (size_t)i * DFF_ * D, dec_ff1_b + (size_t)i * DFF_,
                qkv_bf, NT, DFF_, D, stream);
        gemmln(qkv_bf, w_ff2 + (size_t)i * D * DFF_, dec_ff2_b + (size_t)i * D,
               t_f, dec_ln3_g + (size_t)i * D, dec_ln3_b + (size_t)i * D, t_f, t_bf, NT, DFF_, stream);
    }

    hipLaunchKernelGGL(ln_kernel, dim3(NT), dim3(64), 0, stream,
                       t_f, (const float*)nullptr, dec_norm_g, dec_norm_b, scf, (u16*)nullptr);
    hipLaunchKernelGGL(fc_kernel, dim3(NT), dim3(64), 0, stream,
                       scf, fc_w, fc_b, (float*)d_out);
}

// Round 6
// 1508.175 us; speedup vs baseline: 32.9717x; 1.0360x over previous
//
#include <hip/hip_runtime.h>
#include <hip/hip_bf16.h>
#include <stdint.h>

#define NH 8

typedef uint16_t u16;
typedef uint32_t u32;
typedef __attribute__((ext_vector_type(8))) short s8b;    // 8 bf16 (4 VGPR)
typedef __attribute__((ext_vector_type(4))) float f32x4;
typedef __attribute__((ext_vector_type(16))) float f32x16;

// exp path: if the exp2 intrinsic exists, fold log2(e) into the Q scale and
// use raw v_exp_f32; else fall back to __expf (v_mul+v_exp).
#if __has_builtin(__builtin_amdgcn_exp2f)
#define EXPS(x) __builtin_amdgcn_exp2f(x)
#define QSCALE 0.36067376022224085f   // 0.25 * log2(e)
#else
#define EXPS(x) __expf(x)
#define QSCALE 0.25f
#endif

// fp32 -> bf16 round-to-nearest-even
__device__ __forceinline__ u16 f2b(float f) {
    u32 u = __builtin_bit_cast(u32, f);
    u = (u + 0x7fffu + ((u >> 16) & 1u)) >> 16;
    return (u16)u;
}

// pack two positive fp32 into 2 bf16 (round-half-up): lo=a, hi=b. 3 VALU ops.
__device__ __forceinline__ u32 pkbf(float a, float b) {
    u32 ua = __builtin_bit_cast(u32, a) + 0x8000u;
    u32 ub = __builtin_bit_cast(u32, b) + 0x8000u;
    return __builtin_amdgcn_perm(ub, ua, 0x07060302);  // {ua.hi16, ub.hi16}
}

// PyTorch-style sinusoidal PE
__device__ __forceinline__ float pe_val(int pos, int d) {
    int j = d >> 1;
    float div = expf((float)j * -0.14391156831212787f);
    float ang = (float)pos * div;
    return (d & 1) ? cosf(ang) : sinf(ang);
}

__global__ void embed_kernel(const int* __restrict__ src, const float* __restrict__ emb,
                             float* __restrict__ S, u16* __restrict__ Sb) {
    int idx = blockIdx.x * 256 + threadIdx.x;
    int d = idx & 127;
    int n = idx >> 7;
    int i = n & 63;
    int tok = src[n];
    float v = emb[tok * 128 + d] * 11.313708498984761f + pe_val(i, d);
    S[idx] = v; Sb[idx] = f2b(v);
}

__global__ void addpe_kernel(const float* __restrict__ tgt, float* __restrict__ T,
                             u16* __restrict__ Tb) {
    int idx = blockIdx.x * 256 + threadIdx.x;
    int d = idx & 127;
    int n = idx >> 7;
    int i = n & 1023;
    float v = tgt[idx] + pe_val(i, d);
    T[idx] = v; Tb[idx] = f2b(v);
}

// Batched fp32->bf16 weight conversion
struct CvtJobs { const float* src[10]; u16* dst[10]; int n[10]; };
__global__ void cvt_kernel(CvtJobs jb) {
    int e = blockIdx.y;
    int i = blockIdx.x * 256 + threadIdx.x;
    if (i < jb.n[e]) jb.dst[e][i] = f2b(jb.src[e][i]);
}

// VT[b][h][n][k] = V[b][k][h*16+n]
__global__ void transposeV(const u16* __restrict__ KV, int stride, int voff,
                           u16* __restrict__ VT, int SKV) {
    int bh = blockIdx.x;
    int k0 = blockIdx.y * 64;
    int l = threadIdx.x;
    int b = bh >> 3, h = bh & 7;
    const u16* p = KV + (size_t)(b * SKV + k0 + l) * stride + voff + h * 16;
    s8b v0 = *(const s8b*)p;
    s8b v1 = *(const s8b*)(p + 8);
    size_t obase = (size_t)bh * 16 * SKV + k0 + l;
#pragma unroll
    for (int n = 0; n < 8; n++) VT[obase + (size_t)n * SKV] = (u16)v0[n];
#pragma unroll
    for (int n = 0; n < 8; n++) VT[obase + (size_t)(n + 8) * SKV] = (u16)v1[n];
}

// C[m,n] = sum_k A[m,k]*W[n,k] + bias[n]; cols < qcols additionally scaled by
// qscale (folds attention 1/sqrt(dh)*log2e into the Q projection).
template <int RELU>
__global__ __launch_bounds__(256) void gemm_mfma(const u16* __restrict__ A,
                                                 const u16* __restrict__ W,
                                                 const float* __restrict__ bias,
                                                 u16* __restrict__ C,
                                                 int M, int N, int K,
                                                 float qscale, int qcols) {
    __shared__ __align__(16) u16 As[128 * 56];
    __shared__ __align__(16) u16 Bs[128 * 56];
    int tid = threadIdx.x;
    int lane = tid & 63, w = tid >> 6;
    int quad = lane >> 4, l15 = lane & 15;
    int m0 = blockIdx.y * 128, n0 = blockIdx.x * 128;
    int wm = (w & 1) * 64, wn = (w >> 1) * 64;
    int srow = tid >> 1, skof = (tid & 1) * 16;

    f32x4 acc[4][4];
#pragma unroll
    for (int i = 0; i < 4; i++)
#pragma unroll
        for (int j = 0; j < 4; j++)
#pragma unroll
            for (int r = 0; r < 4; r++) acc[i][j][r] = 0.f;

    for (int k0 = 0; k0 < K; k0 += 32) {
        const u16* ga = A + (size_t)(m0 + srow) * K + k0 + skof;
        const u16* gw = W + (size_t)(n0 + srow) * K + k0 + skof;
        s8b a0 = *(const s8b*)ga, a1 = *(const s8b*)(ga + 8);
        s8b w0 = *(const s8b*)gw, w1 = *(const s8b*)(gw + 8);
        __syncthreads();
        *(s8b*)(As + srow * 56 + skof) = a0;
        *(s8b*)(As + srow * 56 + skof + 8) = a1;
        *(s8b*)(Bs + srow * 56 + skof) = w0;
        *(s8b*)(Bs + srow * 56 + skof + 8) = w1;
        __syncthreads();
        s8b af[4], bfr[4];
#pragma unroll
        for (int i = 0; i < 4; i++) af[i] = *(const s8b*)(As + (wm + 16 * i + l15) * 56 + quad * 8);
#pragma unroll
        for (int j = 0; j < 4; j++) bfr[j] = *(const s8b*)(Bs + (wn + 16 * j + l15) * 56 + quad * 8);
#pragma unroll
        for (int i = 0; i < 4; i++)
#pragma unroll
            for (int j = 0; j < 4; j++)
                acc[i][j] = __builtin_amdgcn_mfma_f32_16x16x32_bf16(af[i], bfr[j], acc[i][j], 0, 0, 0);
    }
#pragma unroll
    for (int j = 0; j < 4; j++) {
        int col = n0 + wn + 16 * j + l15;
        float bv = bias[col];
        float sc = (col < qcols) ? qscale : 1.f;
#pragma unroll
        for (int i = 0; i < 4; i++) {
            int rbase = m0 + wm + 16 * i + quad * 4;
#pragma unroll
            for (int r = 0; r < 4; r++) {
                float v = (acc[i][j][r] + bv) * sc;
                if (RELU) v = fmaxf(v, 0.f);
                C[(size_t)(rbase + r) * N + col] = f2b(v);
            }
        }
    }
}

// GEMM (N=128) fused with residual-add + LayerNorm.
__global__ __launch_bounds__(256) void gemm_ln(const u16* __restrict__ A,
                                               const u16* __restrict__ W,
                                               const float* __restrict__ bias,
                                               const float* __restrict__ X,
                                               const float* __restrict__ g,
                                               const float* __restrict__ bta,
                                               float* __restrict__ Y,
                                               u16* __restrict__ Yb,
                                               int M, int K) {
    __shared__ __align__(16) u16 As[128 * 56];
    __shared__ __align__(16) u16 Bs[128 * 56];
    __shared__ float redS[128][2], redQ[128][2];
    int tid = threadIdx.x;
    int lane = tid & 63, w = tid >> 6;
    int quad = lane >> 4, l15 = lane & 15;
    int m0 = blockIdx.x * 128;
    int wm = (w & 1) * 64, wn = (w >> 1) * 64;
    int srow = tid >> 1, skof = (tid & 1) * 16;

    f32x4 acc[4][4];
#pragma unroll
    for (int i = 0; i < 4; i++)
#pragma unroll
        for (int j = 0; j < 4; j++)
#pragma unroll
            for (int r = 0; r < 4; r++) acc[i][j][r] = 0.f;

    for (int k0 = 0; k0 < K; k0 += 32) {
        const u16* ga = A + (size_t)(m0 + srow) * K + k0 + skof;
        const u16* gw = W + (size_t)srow * K + k0 + skof;
        s8b a0 = *(const s8b*)ga, a1 = *(const s8b*)(ga + 8);
        s8b w0 = *(const s8b*)gw, w1 = *(const s8b*)(gw + 8);
        __syncthreads();
        *(s8b*)(As + srow * 56 + skof) = a0;
        *(s8b*)(As + srow * 56 + skof + 8) = a1;
        *(s8b*)(Bs + srow * 56 + skof) = w0;
        *(s8b*)(Bs + srow * 56 + skof + 8) = w1;
        __syncthreads();
        s8b af[4], bfr[4];
#pragma unroll
        for (int i = 0; i < 4; i++) af[i] = *(const s8b*)(As + (wm + 16 * i + l15) * 56 + quad * 8);
#pragma unroll
        for (int j = 0; j < 4; j++) bfr[j] = *(const s8b*)(Bs + (wn + 16 * j + l15) * 56 + quad * 8);
#pragma unroll
        for (int i = 0; i < 4; i++)
#pragma unroll
            for (int j = 0; j < 4; j++)
                acc[i][j] = __builtin_amdgcn_mfma_f32_16x16x32_bf16(af[i], bfr[j], acc[i][j], 0, 0, 0);
    }

    float s_[4][4], q_[4][4];
#pragma unroll
    for (int i = 0; i < 4; i++)
#pragma unroll
        for (int r = 0; r < 4; r++) {
            int row = m0 + wm + 16 * i + quad * 4 + r;
            float s = 0.f, q = 0.f;
#pragma unroll
            for (int j = 0; j < 4; j++) {
                int col = wn + 16 * j + l15;
                float x = acc[i][j][r] + bias[col] + X[(size_t)row * 128 + col];
                acc[i][j][r] = x;
                s += x; q += x * x;
            }
#pragma unroll
            for (int off = 1; off < 16; off <<= 1) {
                s += __shfl_xor(s, off);
                q += __shfl_xor(q, off);
            }
            s_[i][r] = s; q_[i][r] = q;
        }
    if (l15 == 0) {
#pragma unroll
        for (int i = 0; i < 4; i++)
#pragma unroll
            for (int r = 0; r < 4; r++) {
                int lrow = wm + 16 * i + quad * 4 + r;
                redS[lrow][wn >> 6] = s_[i][r];
                redQ[lrow][wn >> 6] = q_[i][r];
            }
    }
    __syncthreads();
#pragma unroll
    for (int i = 0; i < 4; i++)
#pragma unroll
        for (int r = 0; r < 4; r++) {
            int lrow = wm + 16 * i + quad * 4 + r;
            int row = m0 + lrow;
            float S2 = redS[lrow][0] + redS[lrow][1];
            float Q2 = redQ[lrow][0] + redQ[lrow][1];
            float mean = S2 * (1.f / 128.f);
            float var = Q2 * (1.f / 128.f) - mean * mean;
            float rstd = rsqrtf(var + 1e-5f);
#pragma unroll
            for (int j = 0; j < 4; j++) {
                int col = wn + 16 * j + l15;
                float y = (acc[i][j][r] - mean) * rstd * g[col] + bta[col];
                Y[(size_t)row * 128 + col] = y;
                Yb[(size_t)row * 128 + col] = f2b(y);
            }
        }
}

// MFMA flash attention v3. Q pre-scaled (QSCALE folded into Q projection).
// S^T = mfma(kf, qf): C col = query, rows = keys -> adjacent regs are adjacent
// keys -> pack 2 bf16/u32, 8 ds_write_b32 per tile. P stored row-major
// [q][key-pairs], row stride 20 u32 (16B aligned). PV/L reads unchanged b128.
template <int WAVES>
__global__ __launch_bounds__(WAVES * 64) void attn3(
    const u16* __restrict__ Qb, int qstride, int qoff,
    const u16* __restrict__ Kb, int kstride, int koff,
    const u16* __restrict__ VT,
    u16* __restrict__ O, int SQ, int SKV) {
    __shared__ __align__(16) u32 Ps[WAVES][32 * 20];
    int tid = threadIdx.x;
    int lane = tid & 63, w = tid >> 6;
    int quad = lane >> 4, l15 = lane & 15, l31 = lane & 31, half = lane >> 5;
    int nqc = SQ / (WAVES * 32);
    int bid = blockIdx.x;
    int qc = bid % nqc;
    int h = (bid / nqc) % NH;
    int b = bid / (nqc * NH);
    int q0 = qc * WAVES * 32 + w * 32;

    const u16* qp = Qb + (size_t)(b * SQ + q0 + l31) * qstride + qoff + h * 16 + half * 8;
    s8b qf = *(const s8b*)qp;
    s8b ones;
#pragma unroll
    for (int j = 0; j < 8; j++) ones[j] = (short)0x3F80;  // bf16 1.0

    const u16* vtb = VT + ((size_t)(b * NH + h) * 16 + l15) * SKV + quad * 8;
    const u16* kp = Kb + (size_t)(b * SKV + l31) * kstride + koff + h * 16 + half * 8;
    size_t kadv = (size_t)32 * kstride;

    f32x4 O0, O1, L0, L1;
#pragma unroll
    for (int r = 0; r < 4; r++) { O0[r] = 0.f; O1[r] = 0.f; L0[r] = 0.f; L1[r] = 0.f; }

    u32* pw = Ps[w];
#pragma unroll 2
    for (int j0 = 0; j0 < SKV; j0 += 32) {
        s8b kf = *(const s8b*)kp;
        kp += kadv;
        s8b vb = *(const s8b*)(vtb + j0);
        f32x16 S;
#pragma unroll
        for (int r = 0; r < 16; r++) S[r] = 0.f;
        S = __builtin_amdgcn_mfma_f32_32x32x16_bf16(kf, qf, S, 0, 0, 0);  // S^T
        // C-layout: col = q = lane&31; row = key = (r&3) + 8*(r>>2) + 4*half
#pragma unroll
        for (int g = 0; g < 4; g++) {
            float p0 = EXPS(S[4 * g + 0]);
            float p1 = EXPS(S[4 * g + 1]);
            float p2 = EXPS(S[4 * g + 2]);
            float p3 = EXPS(S[4 * g + 3]);
            int kw = l31 * 20 + 2 * half + 4 * g;
            pw[kw] = pkbf(p0, p1);
            pw[kw + 1] = pkbf(p2, p3);
        }
        __builtin_amdgcn_wave_barrier();  // wave-private LDS RAW ordering
        s8b pa0 = *(const s8b*)(pw + l15 * 20 + quad * 4);
        s8b pa1 = *(const s8b*)(pw + (16 + l15) * 20 + quad * 4);
        O0 = __builtin_amdgcn_mfma_f32_16x16x32_bf16(pa0, vb, O0, 0, 0, 0);
        O1 = __builtin_amdgcn_mfma_f32_16x16x32_bf16(pa1, vb, O1, 0, 0, 0);
        L0 = __builtin_amdgcn_mfma_f32_16x16x32_bf16(pa0, ones, L0, 0, 0, 0);
        L1 = __builtin_amdgcn_mfma_f32_16x16x32_bf16(pa1, ones, L1, 0, 0, 0);
    }
#pragma unroll
    for (int r = 0; r < 4; r++) {
        int q = b * SQ + q0 + quad * 4 + r;
        O[(size_t)q * 128 + h * 16 + l15] = f2b(O0[r] / L0[r]);
        O[(size_t)(q + 16) * 128 + h * 16 + l15] = f2b(O1[r] / L1[r]);
    }
}

// Standalone LN (enc_norm / dec_norm only)
__global__ void ln_kernel(const float* __restrict__ X, const float* __restrict__ R,
                          const float* __restrict__ g, const float* __restrict__ bta,
                          float* __restrict__ Y, u16* __restrict__ Yb) {
    int r = blockIdx.x;
    int lane = threadIdx.x;
    size_t base = (size_t)r * 128;
    float x0 = X[base + lane], x1 = X[base + lane + 64];
    if (R) { x0 += R[base + lane]; x1 += R[base + lane + 64]; }
    float s = x0 + x1;
    for (int off = 32; off; off >>= 1) s += __shfl_xor(s, off);
    float mean = s * (1.f / 128.f);
    float d0 = x0 - mean, d1 = x1 - mean;
    float vs = d0 * d0 + d1 * d1;
    for (int off = 32; off; off >>= 1) vs += __shfl_xor(vs, off);
    float rstd = rsqrtf(vs * (1.f / 128.f) + 1e-5f);
    float y0 = d0 * rstd * g[lane] + bta[lane];
    float y1 = d1 * rstd * g[lane + 64] + bta[lane + 64];
    Y[base + lane] = y0;
    Y[base + lane + 64] = y1;
    if (Yb) { Yb[base + lane] = f2b(y0); Yb[base + lane + 64] = f2b(y1); }
}

__global__ void fc_kernel(const float* __restrict__ X, const float* __restrict__ w,
                          const float* __restrict__ b, float* __restrict__ out) {
    int r = blockIdx.x;
    int lane = threadIdx.x;
    size_t base = (size_t)r * 128;
    float s = X[base + lane] * w[lane] + X[base + lane + 64] * w[lane + 64];
    for (int off = 32; off; off >>= 1) s += __shfl_xor(s, off);
    if (lane == 0) out[r] = s + b[0];
}

static inline void gemm_b(const u16* A, const u16* W, const float* bias, u16* C,
                          int M, int N, int K, hipStream_t st, int qcols = 0) {
    hipLaunchKernelGGL((gemm_mfma<0>), dim3(N / 128, M / 128), dim3(256), 0, st,
                       A, W, bias, C, M, N, K, QSCALE, qcols);
}
static inline void gemm_br(const u16* A, const u16* W, const float* bias, u16* C,
                           int M, int N, int K, hipStream_t st) {
    hipLaunchKernelGGL((gemm_mfma<1>), dim3(N / 128, M / 128), dim3(256), 0, st,
                       A, W, bias, C, M, N, K, 1.f, 0);
}
static inline void gemmln(const u16* A, const u16* W, const float* bias,
                          const float* X, const float* g, const float* bta,
                          float* Y, u16* Yb, int M, int K, hipStream_t st) {
    hipLaunchKernelGGL(gemm_ln, dim3(M / 128), dim3(256), 0, st,
                       A, W, bias, X, g, bta, Y, Yb, M, K);
}

extern "C" void kernel_launch(void* const* d_in, const int* in_sizes, int n_in,
                              void* d_out, int out_size, void* d_ws, size_t ws_size,
                              hipStream_t stream) {
    const int B = 32, SSRC = 64, STGT = 1024, D = 128, DFF_ = 512, LE = 6, LD = 6;

    const int*   src = (const int*)d_in[0];
    const float* tgt = (const float*)d_in[1];
    const float* emb = (const float*)d_in[2];
    const float* enc_qkv_w = (const float*)d_in[3];
    const float* enc_qkv_b = (const float*)d_in[4];
    const float* enc_out_w = (const float*)d_in[5];
    const float* enc_out_b = (const float*)d_in[6];
    const float* enc_ln1_g = (const float*)d_in[7];
    const float* enc_ln1_b = (const float*)d_in[8];
    const float* enc_ff1_w = (const float*)d_in[9];
    const float* enc_ff1_b = (const float*)d_in[10];
    const float* enc_ff2_w = (const float*)d_in[11];
    const float* enc_ff2_b = (const float*)d_in[12];
    const float* enc_ln2_g = (const float*)d_in[13];
    const float* enc_ln2_b = (const float*)d_in[14];
    const float* enc_norm_g = (const float*)d_in[15];
    const float* enc_norm_b = (const float*)d_in[16];
    const float* dec_sa_qkv_w = (const float*)d_in[17];
    const float* dec_sa_qkv_b = (const float*)d_in[18];
    const float* dec_sa_out_w = (const float*)d_in[19];
    const float* dec_sa_out_b = (const float*)d_in[20];
    const float* dec_ln1_g = (const float*)d_in[21];
    const float* dec_ln1_b = (const float*)d_in[22];
    const float* dec_ca_qkv_w = (const float*)d_in[23];
    const float* dec_ca_qkv_b = (const float*)d_in[24];
    const float* dec_ca_out_w = (const float*)d_in[25];
    const float* dec_ca_out_b = (const float*)d_in[26];
    const float* dec_ln2_g = (const float*)d_in[27];
    const float* dec_ln2_b = (const float*)d_in[28];
    const float* dec_ff1_w = (const float*)d_in[29];
    const float* dec_ff1_b = (const float*)d_in[30];
    const float* dec_ff2_w = (const float*)d_in[31];
    const float* dec_ff2_b = (const float*)d_in[32];
    const float* dec_ln3_g = (const float*)d_in[33];
    const float* dec_ln3_b = (const float*)d_in[34];
    const float* dec_norm_g = (const float*)d_in[35];
    const float* dec_norm_b = (const float*)d_in[36];
    const float* fc_w = (const float*)d_in[37];
    const float* fc_b = (const float*)d_in[38];

    const int NT = B * STGT;   // 32768
    const int NS = B * SSRC;   // 2048

    float* t_f   = (float*)d_ws;
    float* s_f   = t_f + (size_t)NT * D;
    float* mem_f = s_f + (size_t)NS * D;
    u16* t_bf    = (u16*)(mem_f + (size_t)NS * D);
    u16* s_bf    = t_bf + (size_t)NT * D;
    u16* mem_bf  = s_bf + (size_t)NS * D;
    u16* qkv_bf  = mem_bf + (size_t)NS * D;      // 32768*512
    u16* attno_bf = qkv_bf + (size_t)NT * DFF_;  // 32768*128
    u16* ckv_bf  = attno_bf + (size_t)NT * D;    // 2048*256
    u16* vt      = ckv_bf + (size_t)NS * 2 * D;  // B*NH*16*1024
    u16* wa      = vt + (size_t)B * NH * 16 * STGT;

    u16* w_enc_qkv = wa;                          int n_enc_qkv = LE * 3 * D * D;
    u16* w_enc_out = w_enc_qkv + n_enc_qkv;       int n_enc_out = LE * D * D;
    u16* w_enc_ff1 = w_enc_out + n_enc_out;       int n_enc_ff1 = LE * DFF_ * D;
    u16* w_enc_ff2 = w_enc_ff1 + n_enc_ff1;       int n_enc_ff2 = LE * D * DFF_;
    u16* w_sa_qkv  = w_enc_ff2 + n_enc_ff2;       int n_sa_qkv = LD * 3 * D * D;
    u16* w_sa_out  = w_sa_qkv + n_sa_qkv;         int n_sa_out = LD * D * D;
    u16* w_ca_qkv  = w_sa_out + n_sa_out;         int n_ca_qkv = LD * 3 * D * D;
    u16* w_ca_out  = w_ca_qkv + n_ca_qkv;         int n_ca_out = LD * D * D;
    u16* w_ff1     = w_ca_out + n_ca_out;         int n_ff1 = LD * DFF_ * D;
    u16* w_ff2     = w_ff1 + n_ff1;               int n_ff2 = LD * D * DFF_;

    float* scf = (float*)qkv_bf;

    CvtJobs jb;
    jb.src[0] = enc_qkv_w;    jb.dst[0] = w_enc_qkv; jb.n[0] = n_enc_qkv;
    jb.src[1] = enc_out_w;    jb.dst[1] = w_enc_out; jb.n[1] = n_enc_out;
    jb.src[2] = enc_ff1_w;    jb.dst[2] = w_enc_ff1; jb.n[2] = n_enc_ff1;
    jb.src[3] = enc_ff2_w;    jb.dst[3] = w_enc_ff2; jb.n[3] = n_enc_ff2;
    jb.src[4] = dec_sa_qkv_w; jb.dst[4] = w_sa_qkv;  jb.n[4] = n_sa_qkv;
    jb.src[5] = dec_sa_out_w; jb.dst[5] = w_sa_out;  jb.n[5] = n_sa_out;
    jb.src[6] = dec_ca_qkv_w; jb.dst[6] = w_ca_qkv;  jb.n[6] = n_ca_qkv;
    jb.src[7] = dec_ca_out_w; jb.dst[7] = w_ca_out;  jb.n[7] = n_ca_out;
    jb.src[8] = dec_ff1_w;    jb.dst[8] = w_ff1;     jb.n[8] = n_ff1;
    jb.src[9] = dec_ff2_w;    jb.dst[9] = w_ff2;     jb.n[9] = n_ff2;
    int maxn = n_enc_ff1;
    hipLaunchKernelGGL(cvt_kernel, dim3((maxn + 255) / 256, 10), dim3(256), 0, stream, jb);

    // ---------------- Encoder ----------------
    hipLaunchKernelGGL(embed_kernel, dim3(NS * D / 256), dim3(256), 0, stream, src, emb, s_f, s_bf);

    for (int i = 0; i < LE; i++) {
        gemm_b(s_bf, w_enc_qkv + (size_t)i * 3 * D * D, enc_qkv_b + (size_t)i * 3 * D,
               qkv_bf, NS, 3 * D, D, stream, 128);  // Q cols pre-scaled
        hipLaunchKernelGGL(transposeV, dim3(B * NH, 1), dim3(64), 0, stream,
                           qkv_bf, 3 * D, 2 * D, vt, SSRC);
        hipLaunchKernelGGL((attn3<2>), dim3(B * NH), dim3(128), 0, stream,
                           qkv_bf, 3 * D, 0, qkv_bf, 3 * D, D, vt, attno_bf, SSRC, SSRC);
        gemmln(attno_bf, w_enc_out + (size_t)i * D * D, enc_out_b + (size_t)i * D,
               s_f, enc_ln1_g + (size_t)i * D, enc_ln1_b + (size_t)i * D, s_f, s_bf, NS, D, stream);
        gemm_br(s_bf, w_enc_ff1 + (size_t)i * DFF_ * D, enc_ff1_b + (size_t)i * DFF_,
                qkv_bf, NS, DFF_, D, stream);
        gemmln(qkv_bf, w_enc_ff2 + (size_t)i * D * DFF_, enc_ff2_b + (size_t)i * D,
               s_f, enc_ln2_g + (size_t)i * D, enc_ln2_b + (size_t)i * D, s_f, s_bf, NS, DFF_, stream);
    }
    hipLaunchKernelGGL(ln_kernel, dim3(NS), dim3(64), 0, stream,
                       s_f, (const float*)nullptr, enc_norm_g, enc_norm_b, mem_f, mem_bf);

    // ---------------- Decoder ----------------
    hipLaunchKernelGGL(addpe_kernel, dim3(NT * D / 256), dim3(256), 0, stream, tgt, t_f, t_bf);

    for (int i = 0; i < LD; i++) {
        // self-attention
        gemm_b(t_bf, w_sa_qkv + (size_t)i * 3 * D * D, dec_sa_qkv_b + (size_t)i * 3 * D,
               qkv_bf, NT, 3 * D, D, stream, 128);
        hipLaunchKernelGGL(transposeV, dim3(B * NH, STGT / 64), dim3(64), 0, stream,
                           qkv_bf, 3 * D, 2 * D, vt, STGT);
        hipLaunchKernelGGL((attn3<4>), dim3(B * NH * (STGT / 128)), dim3(256), 0, stream,
                           qkv_bf, 3 * D, 0, qkv_bf, 3 * D, D, vt, attno_bf, STGT, STGT);
        gemmln(attno_bf, w_sa_out + (size_t)i * D * D, dec_sa_out_b + (size_t)i * D,
               t_f, dec_ln1_g + (size_t)i * D, dec_ln1_b + (size_t)i * D, t_f, t_bf, NT, D, stream);

        // cross-attention
        gemm_b(t_bf, w_ca_qkv + (size_t)i * 3 * D * D, dec_ca_qkv_b + (size_t)i * 3 * D,
               qkv_bf, NT, D, D, stream, 128);  // Q only, pre-scaled
        gemm_b(mem_bf, w_ca_qkv + (size_t)i * 3 * D * D + (size_t)D * D,
               dec_ca_qkv_b + (size_t)i * 3 * D + D, ckv_bf, NS, 2 * D, D, stream);  // K,V
        hipLaunchKernelGGL(transposeV, dim3(B * NH, 1), dim3(64), 0, stream,
                           ckv_bf, 2 * D, D, vt, SSRC);
        hipLaunchKernelGGL((attn3<4>), dim3(B * NH * (STGT / 128)), dim3(256), 0, stream,
                           qkv_bf, D, 0, ckv_bf, 2 * D, 0, vt, attno_bf, STGT, SSRC);
        gemmln(attno_bf, w_ca_out + (size_t)i * D * D, dec_ca_out_b + (size_t)i * D,
               t_f, dec_ln2_g + (size_t)i * D, dec_ln2_b + (size_t)i * D, t_f, t_bf, NT, D, stream);

        // FFN
        gemm_br(t_bf, w_ff1 + (size_t)i * DFF_ * D, dec_ff1_b + (size_t)i * DFF_,
                qkv_bf, NT, DFF_, D, stream);
        gemmln(qkv_bf, w_ff2 + (size_t)i * D * DFF_, dec_ff2_b + (size_t)i * D,
               t_f, dec_ln3_g + (size_t)i * D, dec_ln3_b + (size_t)i * D, t_f, t_bf, NT, DFF_, stream);
    }

    hipLaunchKernelGGL(ln_kernel, dim3(NT), dim3(64), 0, stream,
                       t_f, (const float*)nullptr, dec_norm_g, dec_norm_b, scf, (u16*)nullptr);
    hipLaunchKernelGGL(fc_kernel, dim3(NT), dim3(64), 0, stream,
                       scf, fc_w, fc_b, (float*)d_out);
}